// Round 3
// baseline (2765.852 us; speedup 1.0000x reference)
//
#include <hip/hip_runtime.h>
#include <math.h>

// Problem constants
#define B_  128
#define V_  30000
#define T_  50
#define K_  50
#define HE_ 256
#define TH_ 800
#define E_  300
#define L_  3

#define LOGD_ (-5.2983173665480363f)   // log(0.005) in f32

typedef short bf16x8 __attribute__((ext_vector_type(8)));
typedef float f32x4  __attribute__((ext_vector_type(4)));

// ---------------------------------------------------------------------------
// Generic f32 NT GEMM: C[M,N] = A[M,K] * B[N,K]^T  (A,B row-major, K contiguous)
// mode: 0 = plain store, 1 = tanh(x + bias[col]), 2 = x + bias[col]
//       3 = split-K atomic accumulate (C must be pre-zeroed; bias ignored)
// ---------------------------------------------------------------------------
#define TM 64
#define TN 64
#define TK 16

__global__ __launch_bounds__(256) void gemm_nt(
    const float* __restrict__ A, int lda, int M,
    const float* __restrict__ B, int ldb, int N,
    int K,
    float* __restrict__ C, int ldc,
    const float* __restrict__ bias, int mode, int kchunk)
{
    __shared__ float As[TK][TM + 4];
    __shared__ float Bs[TK][TN + 4];
    const int tid = threadIdx.x;
    const int bm = blockIdx.y * TM;
    const int bn = blockIdx.x * TN;
    const int tx = tid & 15;       // 0..15 col group
    const int ty = tid >> 4;       // 0..15 row group
    const int lr = tid >> 2;       // 0..63 tile row for loads
    const int lc = (tid & 3) << 2; // 0,4,8,12 k offset for loads

    float acc[4][4];
#pragma unroll
    for (int i = 0; i < 4; ++i)
#pragma unroll
        for (int j = 0; j < 4; ++j) acc[i][j] = 0.f;

    const int kbeg = blockIdx.z * kchunk;
    const int kend = min(K, kbeg + kchunk);

    for (int k0 = kbeg; k0 < kend; k0 += TK) {
        // stage A tile
        {
            float v0 = 0.f, v1 = 0.f, v2 = 0.f, v3 = 0.f;
            int gr = bm + lr;
            if (gr < M) {
                const float* p = A + (size_t)gr * lda + k0 + lc;
                int rem = K - (k0 + lc);
                if (rem >= 4) {
                    float2 a0 = *(const float2*)p;
                    float2 a1 = *(const float2*)(p + 2);
                    v0 = a0.x; v1 = a0.y; v2 = a1.x; v3 = a1.y;
                } else {
                    if (rem > 0) v0 = p[0];
                    if (rem > 1) v1 = p[1];
                    if (rem > 2) v2 = p[2];
                }
            }
            As[lc + 0][lr] = v0; As[lc + 1][lr] = v1;
            As[lc + 2][lr] = v2; As[lc + 3][lr] = v3;
        }
        // stage B tile
        {
            float v0 = 0.f, v1 = 0.f, v2 = 0.f, v3 = 0.f;
            int gr = bn + lr;
            if (gr < N) {
                const float* p = B + (size_t)gr * ldb + k0 + lc;
                int rem = K - (k0 + lc);
                if (rem >= 4) {
                    float2 a0 = *(const float2*)p;
                    float2 a1 = *(const float2*)(p + 2);
                    v0 = a0.x; v1 = a0.y; v2 = a1.x; v3 = a1.y;
                } else {
                    if (rem > 0) v0 = p[0];
                    if (rem > 1) v1 = p[1];
                    if (rem > 2) v2 = p[2];
                }
            }
            Bs[lc + 0][lr] = v0; Bs[lc + 1][lr] = v1;
            Bs[lc + 2][lr] = v2; Bs[lc + 3][lr] = v3;
        }
        __syncthreads();
#pragma unroll
        for (int kk = 0; kk < TK; ++kk) {
            float a[4], b[4];
#pragma unroll
            for (int i = 0; i < 4; ++i) a[i] = As[kk][ty * 4 + i];
#pragma unroll
            for (int j = 0; j < 4; ++j) b[j] = Bs[kk][tx * 4 + j];
#pragma unroll
            for (int i = 0; i < 4; ++i)
#pragma unroll
                for (int j = 0; j < 4; ++j) acc[i][j] += a[i] * b[j];
        }
        __syncthreads();
    }

#pragma unroll
    for (int i = 0; i < 4; ++i) {
        int row = bm + ty * 4 + i;
        if (row >= M) continue;
#pragma unroll
        for (int j = 0; j < 4; ++j) {
            int col = bn + tx * 4 + j;
            if (col >= N) continue;
            float v = acc[i][j];
            if (mode == 3) {
                atomicAdd(&C[(size_t)row * ldc + col], v);
            } else {
                if (mode == 1) v = tanhf(v + bias[col]);
                else if (mode == 2) v = v + bias[col];
                C[(size_t)row * ldc + col] = v;
            }
        }
    }
}

// ---------------------------------------------------------------------------
// Epilogue for split-K GEMMs: C[i] = (tanh)(C[i] + bias[col]).
// ---------------------------------------------------------------------------
__global__ __launch_bounds__(256) void bias_act(
    float* __restrict__ C, const float* __restrict__ bias,
    int total, int N, int mode)
{
    int idx = blockIdx.x * 256 + threadIdx.x;
    if (idx >= total) return;
    int j = idx % N;
    float v = C[idx] + bias[j];
    if (mode == 1) v = tanhf(v);
    C[idx] = v;
}

// ---------------------------------------------------------------------------
// Row sums of X -> 1/sum
// ---------------------------------------------------------------------------
__global__ __launch_bounds__(256) void rowsum_inv(const float* __restrict__ X,
                                                  float* __restrict__ inv)
{
    int b = blockIdx.x;
    const float4* p = (const float4*)(X + (size_t)b * V_);
    float s = 0.f;
    for (int i = threadIdx.x; i < V_ / 4; i += 256) {
        float4 v = p[i];
        s += v.x + v.y + v.z + v.w;
    }
    for (int off = 32; off; off >>= 1) s += __shfl_down(s, off);
    __shared__ float red[4];
    int wid = threadIdx.x >> 6, lane = threadIdx.x & 63;
    if (lane == 0) red[wid] = s;
    __syncthreads();
    if (threadIdx.x == 0) inv[b] = 1.f / (red[0] + red[1] + red[2] + red[3]);
}

// ---------------------------------------------------------------------------
// Fused 3-layer LSTM, 32 blocks cooperating via device-scope atomic barrier.
// ---------------------------------------------------------------------------
#define NLB 32

__global__ __launch_bounds__(256) void lstm_all(
    const float* __restrict__ rnn_in,   // [T,HE] layer-0 input
    const float* __restrict__ Wih,      // [L,4HE,HE]
    const float* __restrict__ Whh,      // [L,4HE,HE]
    const float* __restrict__ bih,      // [L,4HE]
    const float* __restrict__ bhh,      // [L,4HE]
    float* __restrict__ houtA,          // [T,HE] layer-0 out
    float* __restrict__ houtB,          // [T,HE] layer-1 out
    float* __restrict__ houtF,          // [T,HE] layer-2 out (final)
    float* __restrict__ hping,          // [2,HE]
    int* __restrict__ barcnt)           // zeroed before launch
{
    __shared__ float sx[8 * 36];  // 8 segments of 32 floats, stride 36 (bank pad)
    __shared__ float sh[8 * 36];
    __shared__ float sg[32];
    const int tid = threadIdx.x;
    const int blk = blockIdx.x;
    const int row_local = tid >> 3;        // 0..31
    const int chunk = tid & 7;             // 0..7
    const int gate = row_local >> 3;       // 0..3 (i,f,g,o)
    const int jloc = row_local & 7;        // 0..7
    const int gr = gate * HE_ + blk * 8 + jloc;  // global gate row 0..1023
    const int seg = tid >> 5, sidx = tid & 31;

    for (int l = 0; l < L_; ++l) {
        float4 wih[8], whh[8];
        const float4* pi = (const float4*)(Wih + ((size_t)l * 4 * HE_ + gr) * HE_ + chunk * 32);
        const float4* pw = (const float4*)(Whh + ((size_t)l * 4 * HE_ + gr) * HE_ + chunk * 32);
#pragma unroll
        for (int q = 0; q < 8; ++q) { wih[q] = pi[q]; whh[q] = pw[q]; }
        const float bias = bih[l * 4 * HE_ + gr] + bhh[l * 4 * HE_ + gr];
        const float* xs = (l == 0) ? rnn_in : ((l == 1) ? houtA : houtB);
        float* hd = (l == 0) ? houtA : ((l == 1) ? houtB : houtF);
        float cst = 0.f;

        for (int t = 0; t < T_; ++t) {
            const int wb = t & 1, rb = wb ^ 1;
            float xv = xs[t * HE_ + tid];
            float hv = (t > 0) ? hping[rb * HE_ + tid] : 0.f;
            sx[seg * 36 + sidx] = xv;
            sh[seg * 36 + sidx] = hv;
            __syncthreads();

            float acc = 0.f;
#pragma unroll
            for (int q = 0; q < 8; ++q) {
                float4 a = *(const float4*)&sx[chunk * 36 + q * 4];
                float4 b = *(const float4*)&sh[chunk * 36 + q * 4];
                float4 wa = wih[q], wc = whh[q];
                acc += wa.x * a.x + wa.y * a.y + wa.z * a.z + wa.w * a.w
                     + wc.x * b.x + wc.y * b.y + wc.z * b.z + wc.w * b.w;
            }
            acc += __shfl_xor(acc, 1);
            acc += __shfl_xor(acc, 2);
            acc += __shfl_xor(acc, 4);
            if (chunk == 0) sg[row_local] = acc + bias;
            __syncthreads();

            if (tid < 8) {
                float gi = sg[tid], gf = sg[8 + tid], gg = sg[16 + tid], go = sg[24 + tid];
                float si = 1.f / (1.f + expf(-gi));
                float sf = 1.f / (1.f + expf(-gf));
                float so = 1.f / (1.f + expf(-go));
                cst = sf * cst + si * tanhf(gg);
                float hn = so * tanhf(cst);
                int j = blk * 8 + tid;
                hping[wb * HE_ + j] = hn;
                hd[t * HE_ + j] = hn;
            }

            // grid barrier (release, arrive, spin, acquire)
            if (tid < 64) __threadfence();
            __syncthreads();
            if (tid == 0) {
                atomicAdd(barcnt, 1);
                const int tgt = (l * T_ + t + 1) * NLB;
                while (atomicAdd(barcnt, 0) < tgt) __builtin_amdgcn_s_sleep(2);
                __threadfence();
            }
            __syncthreads();
        }
    }
}

// ---------------------------------------------------------------------------
// Sequential eta recurrence, wave-parallel dots: 256 threads, 4 lanes per k.
// ---------------------------------------------------------------------------
__global__ __launch_bounds__(256) void eta_scan(
    const float* __restrict__ rnn_out,  // [T,HE]
    const float* __restrict__ Wmu, const float* __restrict__ bmu,
    const float* __restrict__ Wls, const float* __restrict__ bls,
    float* __restrict__ etas,           // [T,K]
    float* __restrict__ kl_eta_out)
{
    __shared__ float hbuf[HE_ + K_];
    __shared__ float smu[K_];
    __shared__ float red[256];
    const int tid = threadIdx.x;
    const int k = tid >> 2, c = tid & 3;
    if (tid < K_) hbuf[HE_ + tid] = 0.f;
    float kl = 0.f;
    __syncthreads();
    for (int t = 0; t < T_; ++t) {
        if (tid < HE_) hbuf[tid] = rnn_out[t * HE_ + tid];
        __syncthreads();
        if (k < K_) {
            const float* wm = Wmu + k * (HE_ + K_);
            const float* wl = Wls + k * (HE_ + K_);
            float am = 0.f, al = 0.f;
            for (int i = c; i < HE_ + K_; i += 4) {
                float hv = hbuf[i];
                am += wm[i] * hv;
                al += wl[i] * hv;
            }
            am += __shfl_xor(am, 1); am += __shfl_xor(am, 2);
            al += __shfl_xor(al, 1); al += __shfl_xor(al, 2);
            if (c == 0) {
                float mu = am + bmu[k];
                float ls = al + bls[k];
                float eprev = hbuf[HE_ + k];
                float pls = (t == 0) ? 0.f : LOGD_;
                float d = mu - eprev;
                kl += 0.5f * ((expf(ls) + d * d) / (expf(pls) + 1e-6f) - 1.f + pls - ls);
                etas[t * K_ + k] = mu;
                smu[k] = mu;
            }
        }
        __syncthreads();
        if (tid < K_) hbuf[HE_ + tid] = smu[tid];
        __syncthreads();
    }
    red[tid] = kl;
    __syncthreads();
    if (tid == 0) {
        float s = 0.f;
        for (int i = 0; i < 256; ++i) s += red[i];
        *kl_eta_out = s;
    }
}

// ---------------------------------------------------------------------------
// h1 = tanh(inv[b]*C1 + etas[ts[b]]·W1[:,V:] + b1)   (in place on C1)
// ---------------------------------------------------------------------------
__global__ __launch_bounds__(256) void h1_epilogue(
    const float* __restrict__ C1, const float* __restrict__ inv,
    const float* __restrict__ etas, const int* __restrict__ ts,
    const float* __restrict__ W1, const float* __restrict__ b1,
    float* __restrict__ h1)
{
    int idx = blockIdx.x * 256 + threadIdx.x;
    if (idx >= B_ * TH_) return;
    int b = idx / TH_, j = idx % TH_;
    const float* e = etas + ts[b] * K_;
    const float* w = W1 + (size_t)j * (V_ + K_) + V_;
    float s = 0.f;
#pragma unroll
    for (int k = 0; k < K_; ++k) s += e[k] * w[k];
    h1[idx] = tanhf(C1[idx] * inv[b] + s + b1[j]);
}

// ---------------------------------------------------------------------------
// theta = softmax(mu_t) rows; kl_theta accumulated. One block (1 wave) per b.
// ---------------------------------------------------------------------------
__global__ __launch_bounds__(64) void theta_kernel(
    const float* __restrict__ mu_t, const float* __restrict__ ls_t,
    const float* __restrict__ etas, const int* __restrict__ ts,
    float* __restrict__ theta, float* __restrict__ kl_out)
{
    int b = blockIdx.x;
    int lane = threadIdx.x;
    bool ok = lane < K_;
    float m = ok ? mu_t[b * K_ + lane] : -3.4e38f;
    float mx = m;
    for (int off = 32; off; off >>= 1) mx = fmaxf(mx, __shfl_down(mx, off));
    mx = __shfl(mx, 0);
    float e = ok ? expf(m - mx) : 0.f;
    float s = e;
    for (int off = 32; off; off >>= 1) s += __shfl_down(s, off);
    s = __shfl(s, 0);
    if (ok) theta[b * K_ + lane] = e / s;
    float kl = 0.f;
    if (ok) {
        float ls = ls_t[b * K_ + lane];
        float d = m - etas[ts[b] * K_ + lane];
        kl = 0.5f * ((expf(ls) + d * d) / (1.f + 1e-6f) - 1.f - ls);
    }
    for (int off = 32; off; off >>= 1) kl += __shfl_down(kl, off);
    if (lane == 0) atomicAdd(kl_out, kl);
}

// ---------------------------------------------------------------------------
// alpha transpose + bf16 hi/lo split into padded [MPAD,KP] operand.
// row = t*K + k holds mu_q_alpha[k,t,:]; pad rows/cols are zero.
// ---------------------------------------------------------------------------
#define KP_   320
#define MPAD_ 2560
#define NPAD_ 30080

__global__ __launch_bounds__(256) void conv_alpha(
    const float* __restrict__ mu, short* __restrict__ Ah, short* __restrict__ Al)
{
    int idx = blockIdx.x * 256 + threadIdx.x;
    if (idx >= MPAD_ * KP_) return;
    int row = idx / KP_, e = idx % KP_;
    float v = 0.f;
    if (row < T_ * K_ && e < E_) {
        int t = row / K_, k = row % K_;
        v = mu[((size_t)k * T_ + t) * E_ + e];
    }
    unsigned int u = __float_as_uint(v);
    Ah[idx] = (short)(u >> 16);
    float hf = __uint_as_float(u & 0xFFFF0000u);
    Al[idx] = (short)(__float_as_uint(v - hf) >> 16);
}

// ---------------------------------------------------------------------------
// Beta logits GEMM via split-bf16 MFMA (ahbh + ahbl + albh ~ f32 accuracy).
// C[2500,30000] = alphas[2500,300] @ emb[30000,300]^T, epilogue writes
// exp(logit) and atomically accumulates per-row sums (softmax w/o max:
// logits are O(0.3)).  Tiles: BM=BN=128, BK=64; 4 waves; LDS XOR-swizzled
// (slot = r*8 + (k8 ^ (r&7)), 128B rows -> 2-way conflicts = free).
// B is converted f32->bf16 hi/lo on the fly during staging.
// ---------------------------------------------------------------------------
__global__ __launch_bounds__(256) void gemm_beta(
    const short* __restrict__ Ah, const short* __restrict__ Al,
    const float* __restrict__ Bf,   // emb [30000,300]
    float* __restrict__ Cexp,       // o_beta gets exp(logit)
    float* __restrict__ bsum)       // [2500] zeroed
{
    __shared__ __align__(16) short lds[4 * 8192];  // Ah,Al,Bh,Bl tiles (16KB each)
    const int tid = threadIdx.x;
    const int lane = tid & 63;
    const int w = tid >> 6;
    const int wr = w >> 1, wc = w & 1;
    const int bm = blockIdx.y * 128;
    const int bn = blockIdx.x * 128;
    const int l15 = lane & 15, l4 = lane >> 4;

    f32x4 acc[4][4];
#pragma unroll
    for (int mi = 0; mi < 4; ++mi)
#pragma unroll
        for (int ni = 0; ni < 4; ++ni) acc[mi][ni] = (f32x4){0.f, 0.f, 0.f, 0.f};

    for (int k0 = 0; k0 < KP_; k0 += 64) {
        // ---- stage A hi/lo (2048 x 16B chunks, swizzled dest == linear here:
        //      dest slot c; source k-group chosen so that slot = r*8 + (k8^(r&7)))
#pragma unroll
        for (int q = 0; q < 8; ++q) {
            int L = q * 256 + tid;
            int tile = L >> 10;            // 0=Ah, 1=Al
            int c = L & 1023;
            int r = c >> 3;
            int k8 = (c & 7) ^ (r & 7);
            const short* src = (tile ? Al : Ah) + (size_t)(bm + r) * KP_ + k0 + k8 * 8;
            *(uint4*)&lds[(size_t)(tile * 1024 + c) * 8] = *(const uint4*)src;
        }
        // ---- stage B with on-the-fly f32 -> bf16 hi/lo split (1024 chunks)
#pragma unroll
        for (int q = 0; q < 4; ++q) {
            int L = q * 256 + tid;
            int r = L >> 3;
            int k8 = (L & 7) ^ (r & 7);
            int rg = bn + r;
            int kb = k0 + k8 * 8;
            float vv[8];
            if (rg < V_ && kb + 8 <= E_) {
                float4 u0 = *(const float4*)(Bf + (size_t)rg * E_ + kb);
                float4 u1 = *(const float4*)(Bf + (size_t)rg * E_ + kb + 4);
                vv[0] = u0.x; vv[1] = u0.y; vv[2] = u0.z; vv[3] = u0.w;
                vv[4] = u1.x; vv[5] = u1.y; vv[6] = u1.z; vv[7] = u1.w;
            } else {
#pragma unroll
                for (int e = 0; e < 8; ++e) {
                    int kk = kb + e;
                    vv[e] = (rg < V_ && kk < E_) ? Bf[(size_t)rg * E_ + kk] : 0.f;
                }
            }
            unsigned int hpk[4], lpk[4];
#pragma unroll
            for (int e = 0; e < 8; e += 2) {
                unsigned int u0 = __float_as_uint(vv[e]);
                unsigned int u1 = __float_as_uint(vv[e + 1]);
                hpk[e >> 1] = (u0 >> 16) | (u1 & 0xFFFF0000u);
                float d0 = vv[e]     - __uint_as_float(u0 & 0xFFFF0000u);
                float d1 = vv[e + 1] - __uint_as_float(u1 & 0xFFFF0000u);
                lpk[e >> 1] = (__float_as_uint(d0) >> 16) | (__float_as_uint(d1) & 0xFFFF0000u);
            }
            uint4 hv; hv.x = hpk[0]; hv.y = hpk[1]; hv.z = hpk[2]; hv.w = hpk[3];
            uint4 lv; lv.x = lpk[0]; lv.y = lpk[1]; lv.z = lpk[2]; lv.w = lpk[3];
            *(uint4*)&lds[(size_t)(2048 + L) * 8] = hv;
            *(uint4*)&lds[(size_t)(3072 + L) * 8] = lv;
        }
        __syncthreads();

#pragma unroll
        for (int ks = 0; ks < 2; ++ks) {
            bf16x8 fah[4], fal[4], fbh[4], fbl[4];
#pragma unroll
            for (int mi = 0; mi < 4; ++mi) {
                int r = wr * 64 + mi * 16 + l15;
                int s = r * 8 + ((ks * 4 + l4) ^ (r & 7));
                fah[mi] = *(const bf16x8*)&lds[(size_t)s * 8];
                fal[mi] = *(const bf16x8*)&lds[(size_t)(1024 + s) * 8];
            }
#pragma unroll
            for (int ni = 0; ni < 4; ++ni) {
                int r = wc * 64 + ni * 16 + l15;
                int s = r * 8 + ((ks * 4 + l4) ^ (r & 7));
                fbh[ni] = *(const bf16x8*)&lds[(size_t)(2048 + s) * 8];
                fbl[ni] = *(const bf16x8*)&lds[(size_t)(3072 + s) * 8];
            }
#pragma unroll
            for (int mi = 0; mi < 4; ++mi)
#pragma unroll
                for (int ni = 0; ni < 4; ++ni) {
                    acc[mi][ni] = __builtin_amdgcn_mfma_f32_16x16x32_bf16(
                        fah[mi], fbh[ni], acc[mi][ni], 0, 0, 0);
                    acc[mi][ni] = __builtin_amdgcn_mfma_f32_16x16x32_bf16(
                        fah[mi], fbl[ni], acc[mi][ni], 0, 0, 0);
                    acc[mi][ni] = __builtin_amdgcn_mfma_f32_16x16x32_bf16(
                        fal[mi], fbh[ni], acc[mi][ni], 0, 0, 0);
                }
        }
        __syncthreads();
    }

    // ---- epilogue: exp, store, per-row sum (C/D: col=lane&15, row=(lane>>4)*4+reg)
#pragma unroll
    for (int mi = 0; mi < 4; ++mi) {
#pragma unroll
        for (int reg = 0; reg < 4; ++reg) {
            int grow = bm + wr * 64 + mi * 16 + (l4 << 2) + reg;
            float rs = 0.f;
            float ex[4];
#pragma unroll
            for (int ni = 0; ni < 4; ++ni) {
                int gcol = bn + wc * 64 + ni * 16 + l15;
                float e = (gcol < V_) ? __expf(acc[mi][ni][reg]) : 0.f;
                ex[ni] = e;
                rs += e;
            }
            if (grow < T_ * K_) {
#pragma unroll
                for (int ni = 0; ni < 4; ++ni) {
                    int gcol = bn + wc * 64 + ni * 16 + l15;
                    if (gcol < V_) Cexp[(size_t)grow * V_ + gcol] = ex[ni];
                }
            }
            rs += __shfl_xor(rs, 1);
            rs += __shfl_xor(rs, 2);
            rs += __shfl_xor(rs, 4);
            rs += __shfl_xor(rs, 8);
            if (l15 == 0 && grow < T_ * K_) atomicAdd(&bsum[grow], rs);
        }
    }
}

// ---------------------------------------------------------------------------
// beta[row][:] *= 1/bsum[row]  (softmax normalization)
// ---------------------------------------------------------------------------
__global__ __launch_bounds__(256) void beta_scale(
    float* __restrict__ beta, const float* __restrict__ bsum)
{
    int row = blockIdx.y;
    int c4 = blockIdx.x * 256 + threadIdx.x;
    if (c4 >= V_ / 4) return;
    float inv = 1.f / bsum[row];
    float4* p = (float4*)(beta + (size_t)row * V_) + c4;
    float4 v = *p;
    v.x *= inv; v.y *= inv; v.z *= inv; v.w *= inv;
    *p = v;
}

// ---------------------------------------------------------------------------
// px / lnpx / nll accumulation. Grid (v-chunks, t). beta[t] staged in LDS.
// ---------------------------------------------------------------------------
__global__ __launch_bounds__(256) void px_kernel(
    const float* __restrict__ beta, const float* __restrict__ theta,
    const int* __restrict__ ts, const float* __restrict__ X,
    float* __restrict__ lnpx, float* __restrict__ nll_acc)
{
    __shared__ float sb[K_][256];
    int t = blockIdx.y;
    int tid = threadIdx.x;
    int v = blockIdx.x * 256 + tid;
    bool vok = v < V_;
    bool any = false;
    for (int b = 0; b < B_; ++b) any |= (ts[b] == t);
    if (!any) return;
    for (int k = 0; k < K_; ++k)
        sb[k][tid] = vok ? beta[((size_t)t * K_ + k) * V_ + v] : 0.f;
    __syncthreads();
    float acc = 0.f;
    for (int b = 0; b < B_; ++b) {
        if (ts[b] != t) continue;
        const float* th = theta + b * K_;
        float px = 0.f;
#pragma unroll
        for (int k = 0; k < K_; ++k) px += th[k] * sb[k][tid];
        float l = logf(px + 1e-6f);
        if (vok) {
            lnpx[(size_t)b * V_ + v] = l;
            acc += l * X[(size_t)b * V_ + v];
        }
    }
    for (int off = 32; off; off >>= 1) acc += __shfl_down(acc, off);
    __shared__ float red[4];
    int wid = tid >> 6, lane = tid & 63;
    if (lane == 0) red[wid] = acc;
    __syncthreads();
    if (tid == 0) atomicAdd(nll_acc, red[0] + red[1] + red[2] + red[3]);
}

// ---------------------------------------------------------------------------
// kl_alpha reduction over (K,T,E) in mu_q_alpha's native layout.
// ---------------------------------------------------------------------------
__global__ __launch_bounds__(256) void kl_alpha_kernel(
    const float* __restrict__ mu, const float* __restrict__ lsig,
    float* __restrict__ out)
{
    int idx = blockIdx.x * 256 + threadIdx.x;
    float term = 0.f;
    if (idx < K_ * T_ * E_) {
        int r = idx % (T_ * E_);
        int t = r / E_;
        float a = mu[idx];
        float q = lsig[idx];
        float pmu = (t > 0) ? mu[idx - E_] : 0.f;
        float pls = (t > 0) ? LOGD_ : 0.f;
        float d = a - pmu;
        term = 0.5f * ((expf(q) + d * d) / (expf(pls) + 1e-6f) - 1.f + pls - q);
    }
    for (int off = 32; off; off >>= 1) term += __shfl_down(term, off);
    __shared__ float red[4];
    int wid = threadIdx.x >> 6, lane = threadIdx.x & 63;
    if (lane == 0) red[wid] = term;
    __syncthreads();
    if (threadIdx.x == 0) atomicAdd(out, red[0] + red[1] + red[2] + red[3]);
}

__global__ void finalize_nll(const float* __restrict__ acc, float* __restrict__ out)
{
    *out = -acc[0] * (1.f / (float)B_);
}

// ---------------------------------------------------------------------------
extern "C" void kernel_launch(void* const* d_in, const int* in_sizes, int n_in,
                              void* d_out, int out_size, void* d_ws, size_t ws_size,
                              hipStream_t stream)
{
    const float* X          = (const float*)d_in[0];
    const int*   ts         = (const int*)d_in[1];
    const float* X_mean     = (const float*)d_in[2];
    const float* W_eta_map  = (const float*)d_in[3];
    const float* b_eta_map  = (const float*)d_in[4];
    const float* lstm_Wih   = (const float*)d_in[5];
    const float* lstm_Whh   = (const float*)d_in[6];
    const float* lstm_bih   = (const float*)d_in[7];
    const float* lstm_bhh   = (const float*)d_in[8];
    const float* W_qeta_mu  = (const float*)d_in[9];
    const float* b_qeta_mu  = (const float*)d_in[10];
    const float* W_qeta_ls  = (const float*)d_in[11];
    const float* b_qeta_ls  = (const float*)d_in[12];
    const float* W1         = (const float*)d_in[13];
    const float* b1         = (const float*)d_in[14];
    const float* W2         = (const float*)d_in[15];
    const float* b2         = (const float*)d_in[16];
    const float* W_qt_mu    = (const float*)d_in[17];
    const float* b_qt_mu    = (const float*)d_in[18];
    const float* W_qt_ls    = (const float*)d_in[19];
    const float* b_qt_ls    = (const float*)d_in[20];
    const float* mu_q_alpha = (const float*)d_in[21];
    const float* ls_q_alpha = (const float*)d_in[22];
    const float* emb        = (const float*)d_in[23];

    float* out     = (float*)d_out;
    float* o_theta = out;                          // [B,K]
    float* o_lnpx  = out + (size_t)B_ * K_;        // [B,V]
    float* o_beta  = o_lnpx + (size_t)B_ * V_;     // [T,K,V]
    float* o_scal  = o_beta + (size_t)T_ * K_ * V_; // nll, kl_alpha, kl_eta, kl_theta

    float* ws = (float*)d_ws;
    float* w_inv   = ws;               // 128
    float* w_rnn   = ws + 128;         // 12800
    float* w_seq0  = ws + 12928;       // 12800  (final LSTM layer out)
    float* w_houtA = ws + 38528;       // 12800  (layer-0 out)
    float* w_houtB = ws + 51328;       // 12800  (layer-1 out)
    float* w_hping = ws + 64128;       // 512
    float* w_barc  = ws + 64640;       // 1 (int)
    float* w_etas  = ws + 89728;       // 2500
    float* w_h1    = ws + 92228;       // 102400
    float* w_h2    = ws + 194628;      // 102400
    float* w_mu    = ws + 297028;      // 6400
    float* w_ls    = ws + 303428;      // 6400
    float* w_nll   = ws + 309828;      // 1
    float* w_bsum  = ws + 309832;      // 2500 (+pad to 312344)
    short* w_Ah    = (short*)(ws + 312344);   // 819200 shorts = 409600 f
    short* w_Al    = (short*)(ws + 721944);   // 819200 shorts = 409600 f
                                              // end: 1131544 floats (~4.5 MB)

    // zero accumulators (d_out / d_ws are poisoned before every launch)
    hipMemsetAsync(o_scal, 0, 4 * sizeof(float), stream);
    hipMemsetAsync(w_h1, 0, (size_t)(102400 + 102400 + 6400 + 6400 + 1) * sizeof(float), stream);
    hipMemsetAsync(w_rnn, 0, (size_t)T_ * HE_ * sizeof(float), stream);
    hipMemsetAsync(w_barc, 0, sizeof(int), stream);
    hipMemsetAsync(w_bsum, 0, (size_t)T_ * K_ * sizeof(float), stream);

    rowsum_inv<<<B_, 256, 0, stream>>>(X, w_inv);

    // rnn_in = X_mean @ W_eta_map^T + b_eta_map   [T,HE], split-K 125x240
    gemm_nt<<<dim3(HE_ / TN, 1, 125), 256, 0, stream>>>(
        X_mean, V_, T_, W_eta_map, V_, HE_, V_, w_rnn, HE_, nullptr, 3, 240);
    bias_act<<<(T_ * HE_ + 255) / 256, 256, 0, stream>>>(
        w_rnn, b_eta_map, T_ * HE_, HE_, 2);

    // fused 3-layer LSTM (input projection fused; grid-barrier per step)
    lstm_all<<<NLB, 256, 0, stream>>>(
        w_rnn, lstm_Wih, lstm_Whh, lstm_bih, lstm_bhh,
        w_houtA, w_houtB, w_seq0, w_hping, (int*)w_barc);

    // eta recurrence + kl_eta
    eta_scan<<<1, 256, 0, stream>>>(w_seq0, W_qeta_mu, b_qeta_mu,
                                    W_qeta_ls, b_qeta_ls, w_etas, o_scal + 2);

    // C1 = X @ W1[:, :V]^T, split-K 75x400; epilogue folds rowsum/eta/bias/tanh
    gemm_nt<<<dim3((TH_ + TN - 1) / TN, (B_ + TM - 1) / TM, 75), 256, 0, stream>>>(
        X, V_, B_, W1, V_ + K_, TH_, V_, w_h1, TH_, nullptr, 3, 400);
    h1_epilogue<<<(B_ * TH_ + 255) / 256, 256, 0, stream>>>(
        w_h1, w_inv, w_etas, ts, W1, b1, w_h1);

    // h2 = tanh(h1 @ W2^T + b2), split-K 10x80
    gemm_nt<<<dim3((TH_ + TN - 1) / TN, (B_ + TM - 1) / TM, 10), 256, 0, stream>>>(
        w_h1, TH_, B_, W2, TH_, TH_, TH_, w_h2, TH_, nullptr, 3, 80);
    bias_act<<<(B_ * TH_ + 255) / 256, 256, 0, stream>>>(
        w_h2, b2, B_ * TH_, TH_, 1);

    // mu_t / ls_t: K=800, split-K 25x32
    gemm_nt<<<dim3(1, (B_ + TM - 1) / TM, 25), 256, 0, stream>>>(
        w_h2, TH_, B_, W_qt_mu, TH_, K_, TH_, w_mu, K_, nullptr, 3, 32);
    gemm_nt<<<dim3(1, (B_ + TM - 1) / TM, 25), 256, 0, stream>>>(
        w_h2, TH_, B_, W_qt_ls, TH_, K_, TH_, w_ls, K_, nullptr, 3, 32);
    bias_act<<<(B_ * K_ + 255) / 256, 256, 0, stream>>>(
        w_mu, b_qt_mu, B_ * K_, K_, 2);
    bias_act<<<(B_ * K_ + 255) / 256, 256, 0, stream>>>(
        w_ls, b_qt_ls, B_ * K_, K_, 2);

    theta_kernel<<<B_, 64, 0, stream>>>(w_mu, w_ls, w_etas, ts, o_theta, o_scal + 3);

    // beta: alpha transpose+split, split-bf16 MFMA GEMM with fused exp/rowsum,
    // then normalize in place
    conv_alpha<<<(MPAD_ * KP_ + 255) / 256, 256, 0, stream>>>(mu_q_alpha, w_Ah, w_Al);
    gemm_beta<<<dim3(NPAD_ / 128, MPAD_ / 128), 256, 0, stream>>>(
        w_Ah, w_Al, emb, o_beta, w_bsum);
    beta_scale<<<dim3((V_ / 4 + 255) / 256, T_ * K_), 256, 0, stream>>>(o_beta, w_bsum);

    // px / lnpx / nll
    px_kernel<<<dim3((V_ + 255) / 256, T_), 256, 0, stream>>>(
        o_beta, o_theta, ts, X, o_lnpx, w_nll);

    kl_alpha_kernel<<<(K_ * T_ * E_ + 255) / 256, 256, 0, stream>>>(
        mu_q_alpha, ls_q_alpha, o_scal + 1);

    finalize_nll<<<1, 1, 0, stream>>>(w_nll, o_scal);
}

// Round 4
// 2572.460 us; speedup vs baseline: 1.0752x; 1.0752x over previous
//
#include <hip/hip_runtime.h>
#include <math.h>

// Problem constants
#define B_  128
#define V_  30000
#define T_  50
#define K_  50
#define HE_ 256
#define TH_ 800
#define E_  300
#define L_  3

#define LOGD_ (-5.2983173665480363f)   // log(0.005) in f32

typedef short bf16x8 __attribute__((ext_vector_type(8)));
typedef float f32x4  __attribute__((ext_vector_type(4)));

// ---------------------------------------------------------------------------
// Generic f32 NT GEMM: C[M,N] = A[M,K] * B[N,K]^T  (A,B row-major, K contiguous)
// mode: 0 = plain store, 1 = tanh(x + bias[col]), 2 = x + bias[col]
//       3 = split-K atomic accumulate (C must be pre-zeroed; bias ignored)
// ---------------------------------------------------------------------------
#define TM 64
#define TN 64
#define TK 16

__global__ __launch_bounds__(256) void gemm_nt(
    const float* __restrict__ A, int lda, int M,
    const float* __restrict__ B, int ldb, int N,
    int K,
    float* __restrict__ C, int ldc,
    const float* __restrict__ bias, int mode, int kchunk)
{
    __shared__ float As[TK][TM + 4];
    __shared__ float Bs[TK][TN + 4];
    const int tid = threadIdx.x;
    const int bm = blockIdx.y * TM;
    const int bn = blockIdx.x * TN;
    const int tx = tid & 15;       // 0..15 col group
    const int ty = tid >> 4;       // 0..15 row group
    const int lr = tid >> 2;       // 0..63 tile row for loads
    const int lc = (tid & 3) << 2; // 0,4,8,12 k offset for loads

    float acc[4][4];
#pragma unroll
    for (int i = 0; i < 4; ++i)
#pragma unroll
        for (int j = 0; j < 4; ++j) acc[i][j] = 0.f;

    const int kbeg = blockIdx.z * kchunk;
    const int kend = min(K, kbeg + kchunk);

    for (int k0 = kbeg; k0 < kend; k0 += TK) {
        // stage A tile
        {
            float v0 = 0.f, v1 = 0.f, v2 = 0.f, v3 = 0.f;
            int gr = bm + lr;
            if (gr < M) {
                const float* p = A + (size_t)gr * lda + k0 + lc;
                int rem = K - (k0 + lc);
                if (rem >= 4) {
                    float2 a0 = *(const float2*)p;
                    float2 a1 = *(const float2*)(p + 2);
                    v0 = a0.x; v1 = a0.y; v2 = a1.x; v3 = a1.y;
                } else {
                    if (rem > 0) v0 = p[0];
                    if (rem > 1) v1 = p[1];
                    if (rem > 2) v2 = p[2];
                }
            }
            As[lc + 0][lr] = v0; As[lc + 1][lr] = v1;
            As[lc + 2][lr] = v2; As[lc + 3][lr] = v3;
        }
        // stage B tile
        {
            float v0 = 0.f, v1 = 0.f, v2 = 0.f, v3 = 0.f;
            int gr = bn + lr;
            if (gr < N) {
                const float* p = B + (size_t)gr * ldb + k0 + lc;
                int rem = K - (k0 + lc);
                if (rem >= 4) {
                    float2 a0 = *(const float2*)p;
                    float2 a1 = *(const float2*)(p + 2);
                    v0 = a0.x; v1 = a0.y; v2 = a1.x; v3 = a1.y;
                } else {
                    if (rem > 0) v0 = p[0];
                    if (rem > 1) v1 = p[1];
                    if (rem > 2) v2 = p[2];
                }
            }
            Bs[lc + 0][lr] = v0; Bs[lc + 1][lr] = v1;
            Bs[lc + 2][lr] = v2; Bs[lc + 3][lr] = v3;
        }
        __syncthreads();
#pragma unroll
        for (int kk = 0; kk < TK; ++kk) {
            float a[4], b[4];
#pragma unroll
            for (int i = 0; i < 4; ++i) a[i] = As[kk][ty * 4 + i];
#pragma unroll
            for (int j = 0; j < 4; ++j) b[j] = Bs[kk][tx * 4 + j];
#pragma unroll
            for (int i = 0; i < 4; ++i)
#pragma unroll
                for (int j = 0; j < 4; ++j) acc[i][j] += a[i] * b[j];
        }
        __syncthreads();
    }

#pragma unroll
    for (int i = 0; i < 4; ++i) {
        int row = bm + ty * 4 + i;
        if (row >= M) continue;
#pragma unroll
        for (int j = 0; j < 4; ++j) {
            int col = bn + tx * 4 + j;
            if (col >= N) continue;
            float v = acc[i][j];
            if (mode == 3) {
                atomicAdd(&C[(size_t)row * ldc + col], v);
            } else {
                if (mode == 1) v = tanhf(v + bias[col]);
                else if (mode == 2) v = v + bias[col];
                C[(size_t)row * ldc + col] = v;
            }
        }
    }
}

// ---------------------------------------------------------------------------
// Epilogue for split-K GEMMs: C[i] = (tanh)(C[i] + bias[col]).
// ---------------------------------------------------------------------------
__global__ __launch_bounds__(256) void bias_act(
    float* __restrict__ C, const float* __restrict__ bias,
    int total, int N, int mode)
{
    int idx = blockIdx.x * 256 + threadIdx.x;
    if (idx >= total) return;
    int j = idx % N;
    float v = C[idx] + bias[j];
    if (mode == 1) v = tanhf(v);
    C[idx] = v;
}

// ---------------------------------------------------------------------------
// Row sums of X -> 1/sum
// ---------------------------------------------------------------------------
__global__ __launch_bounds__(256) void rowsum_inv(const float* __restrict__ X,
                                                  float* __restrict__ inv)
{
    int b = blockIdx.x;
    const float4* p = (const float4*)(X + (size_t)b * V_);
    float s = 0.f;
    for (int i = threadIdx.x; i < V_ / 4; i += 256) {
        float4 v = p[i];
        s += v.x + v.y + v.z + v.w;
    }
    for (int off = 32; off; off >>= 1) s += __shfl_down(s, off);
    __shared__ float red[4];
    int wid = threadIdx.x >> 6, lane = threadIdx.x & 63;
    if (lane == 0) red[wid] = s;
    __syncthreads();
    if (threadIdx.x == 0) inv[b] = 1.f / (red[0] + red[1] + red[2] + red[3]);
}

// ---------------------------------------------------------------------------
// Fused 3-layer LSTM, 32 blocks cooperating via device-scope atomic barrier.
// Spin is a relaxed agent-scope LOAD (not RMW) to avoid 32-way coherence
// serialization on the barrier line.
// ---------------------------------------------------------------------------
#define NLB 32

__global__ __launch_bounds__(256) void lstm_all(
    const float* __restrict__ rnn_in,   // [T,HE] layer-0 input
    const float* __restrict__ Wih,      // [L,4HE,HE]
    const float* __restrict__ Whh,      // [L,4HE,HE]
    const float* __restrict__ bih,      // [L,4HE]
    const float* __restrict__ bhh,      // [L,4HE]
    float* __restrict__ houtA,          // [T,HE] layer-0 out
    float* __restrict__ houtB,          // [T,HE] layer-1 out
    float* __restrict__ houtF,          // [T,HE] layer-2 out (final)
    float* __restrict__ hping,          // [2,HE]
    int* __restrict__ barcnt)           // zeroed before launch
{
    __shared__ float sx[8 * 36];  // 8 segments of 32 floats, stride 36 (bank pad)
    __shared__ float sh[8 * 36];
    __shared__ float sg[32];
    const int tid = threadIdx.x;
    const int blk = blockIdx.x;
    const int row_local = tid >> 3;        // 0..31
    const int chunk = tid & 7;             // 0..7
    const int gate = row_local >> 3;       // 0..3 (i,f,g,o)
    const int jloc = row_local & 7;        // 0..7
    const int gr = gate * HE_ + blk * 8 + jloc;  // global gate row 0..1023
    const int seg = tid >> 5, sidx = tid & 31;

    for (int l = 0; l < L_; ++l) {
        float4 wih[8], whh[8];
        const float4* pi = (const float4*)(Wih + ((size_t)l * 4 * HE_ + gr) * HE_ + chunk * 32);
        const float4* pw = (const float4*)(Whh + ((size_t)l * 4 * HE_ + gr) * HE_ + chunk * 32);
#pragma unroll
        for (int q = 0; q < 8; ++q) { wih[q] = pi[q]; whh[q] = pw[q]; }
        const float bias = bih[l * 4 * HE_ + gr] + bhh[l * 4 * HE_ + gr];
        const float* xs = (l == 0) ? rnn_in : ((l == 1) ? houtA : houtB);
        float* hd = (l == 0) ? houtA : ((l == 1) ? houtB : houtF);
        float cst = 0.f;

        for (int t = 0; t < T_; ++t) {
            const int wb = t & 1, rb = wb ^ 1;
            float xv = xs[t * HE_ + tid];
            float hv = (t > 0) ? hping[rb * HE_ + tid] : 0.f;
            sx[seg * 36 + sidx] = xv;
            sh[seg * 36 + sidx] = hv;
            __syncthreads();

            float acc = 0.f;
#pragma unroll
            for (int q = 0; q < 8; ++q) {
                float4 a = *(const float4*)&sx[chunk * 36 + q * 4];
                float4 b = *(const float4*)&sh[chunk * 36 + q * 4];
                float4 wa = wih[q], wc = whh[q];
                acc += wa.x * a.x + wa.y * a.y + wa.z * a.z + wa.w * a.w
                     + wc.x * b.x + wc.y * b.y + wc.z * b.z + wc.w * b.w;
            }
            acc += __shfl_xor(acc, 1);
            acc += __shfl_xor(acc, 2);
            acc += __shfl_xor(acc, 4);
            if (chunk == 0) sg[row_local] = acc + bias;
            __syncthreads();

            if (tid < 8) {
                float gi = sg[tid], gf = sg[8 + tid], gg = sg[16 + tid], go = sg[24 + tid];
                float si = 1.f / (1.f + expf(-gi));
                float sf = 1.f / (1.f + expf(-gf));
                float so = 1.f / (1.f + expf(-go));
                cst = sf * cst + si * tanhf(gg);
                float hn = so * tanhf(cst);
                int j = blk * 8 + tid;
                hping[wb * HE_ + j] = hn;
                hd[t * HE_ + j] = hn;
            }

            // grid barrier: release fence, arrive (RMW), spin on atomic LOAD
            if (tid < 64) __threadfence();
            __syncthreads();
            if (tid == 0) {
                __hip_atomic_fetch_add(barcnt, 1, __ATOMIC_ACQ_REL, __HIP_MEMORY_SCOPE_AGENT);
                const int tgt = (l * T_ + t + 1) * NLB;
                while (__hip_atomic_load(barcnt, __ATOMIC_ACQUIRE, __HIP_MEMORY_SCOPE_AGENT) < tgt)
                    __builtin_amdgcn_s_sleep(1);
            }
            __syncthreads();
        }
    }
}

// ---------------------------------------------------------------------------
// Sequential eta recurrence, wave-parallel dots: 256 threads, 4 lanes per k.
// ---------------------------------------------------------------------------
__global__ __launch_bounds__(256) void eta_scan(
    const float* __restrict__ rnn_out,  // [T,HE]
    const float* __restrict__ Wmu, const float* __restrict__ bmu,
    const float* __restrict__ Wls, const float* __restrict__ bls,
    float* __restrict__ etas,           // [T,K]
    float* __restrict__ kl_eta_out)
{
    __shared__ float hbuf[HE_ + K_];
    __shared__ float smu[K_];
    __shared__ float red[256];
    const int tid = threadIdx.x;
    const int k = tid >> 2, c = tid & 3;
    if (tid < K_) hbuf[HE_ + tid] = 0.f;
    float kl = 0.f;
    __syncthreads();
    for (int t = 0; t < T_; ++t) {
        if (tid < HE_) hbuf[tid] = rnn_out[t * HE_ + tid];
        __syncthreads();
        if (k < K_) {
            const float* wm = Wmu + k * (HE_ + K_);
            const float* wl = Wls + k * (HE_ + K_);
            float am = 0.f, al = 0.f;
            for (int i = c; i < HE_ + K_; i += 4) {
                float hv = hbuf[i];
                am += wm[i] * hv;
                al += wl[i] * hv;
            }
            am += __shfl_xor(am, 1); am += __shfl_xor(am, 2);
            al += __shfl_xor(al, 1); al += __shfl_xor(al, 2);
            if (c == 0) {
                float mu = am + bmu[k];
                float ls = al + bls[k];
                float eprev = hbuf[HE_ + k];
                float pls = (t == 0) ? 0.f : LOGD_;
                float d = mu - eprev;
                kl += 0.5f * ((expf(ls) + d * d) / (expf(pls) + 1e-6f) - 1.f + pls - ls);
                etas[t * K_ + k] = mu;
                smu[k] = mu;
            }
        }
        __syncthreads();
        if (tid < K_) hbuf[HE_ + tid] = smu[tid];
        __syncthreads();
    }
    red[tid] = kl;
    __syncthreads();
    if (tid == 0) {
        float s = 0.f;
        for (int i = 0; i < 256; ++i) s += red[i];
        *kl_eta_out = s;
    }
}

// ---------------------------------------------------------------------------
// h1 = tanh(inv[b]*C1 + etas[ts[b]]·W1[:,V:] + b1)   (in place on C1)
// ---------------------------------------------------------------------------
__global__ __launch_bounds__(256) void h1_epilogue(
    const float* __restrict__ C1, const float* __restrict__ inv,
    const float* __restrict__ etas, const int* __restrict__ ts,
    const float* __restrict__ W1, const float* __restrict__ b1,
    float* __restrict__ h1)
{
    int idx = blockIdx.x * 256 + threadIdx.x;
    if (idx >= B_ * TH_) return;
    int b = idx / TH_, j = idx % TH_;
    const float* e = etas + ts[b] * K_;
    const float* w = W1 + (size_t)j * (V_ + K_) + V_;
    float s = 0.f;
#pragma unroll
    for (int k = 0; k < K_; ++k) s += e[k] * w[k];
    h1[idx] = tanhf(C1[idx] * inv[b] + s + b1[j]);
}

// ---------------------------------------------------------------------------
// theta = softmax(mu_t) rows; kl_theta accumulated. One block (1 wave) per b.
// ---------------------------------------------------------------------------
__global__ __launch_bounds__(64) void theta_kernel(
    const float* __restrict__ mu_t, const float* __restrict__ ls_t,
    const float* __restrict__ etas, const int* __restrict__ ts,
    float* __restrict__ theta, float* __restrict__ kl_out)
{
    int b = blockIdx.x;
    int lane = threadIdx.x;
    bool ok = lane < K_;
    float m = ok ? mu_t[b * K_ + lane] : -3.4e38f;
    float mx = m;
    for (int off = 32; off; off >>= 1) mx = fmaxf(mx, __shfl_down(mx, off));
    mx = __shfl(mx, 0);
    float e = ok ? expf(m - mx) : 0.f;
    float s = e;
    for (int off = 32; off; off >>= 1) s += __shfl_down(s, off);
    s = __shfl(s, 0);
    if (ok) theta[b * K_ + lane] = e / s;
    float kl = 0.f;
    if (ok) {
        float ls = ls_t[b * K_ + lane];
        float d = m - etas[ts[b] * K_ + lane];
        kl = 0.5f * ((expf(ls) + d * d) / (1.f + 1e-6f) - 1.f - ls);
    }
    for (int off = 32; off; off >>= 1) kl += __shfl_down(kl, off);
    if (lane == 0) atomicAdd(kl_out, kl);
}

// ---------------------------------------------------------------------------
// alpha transpose + bf16 hi/lo split into padded [MPAD,KP] operand.
// ---------------------------------------------------------------------------
#define KP_   320
#define MPAD_ 2560
#define NPAD_ 30080

__global__ __launch_bounds__(256) void conv_alpha(
    const float* __restrict__ mu, short* __restrict__ Ah, short* __restrict__ Al)
{
    int idx = blockIdx.x * 256 + threadIdx.x;
    if (idx >= MPAD_ * KP_) return;
    int row = idx / KP_, e = idx % KP_;
    float v = 0.f;
    if (row < T_ * K_ && e < E_) {
        int t = row / K_, k = row % K_;
        v = mu[((size_t)k * T_ + t) * E_ + e];
    }
    unsigned int u = __float_as_uint(v);
    Ah[idx] = (short)(u >> 16);
    float hf = __uint_as_float(u & 0xFFFF0000u);
    Al[idx] = (short)(__float_as_uint(v - hf) >> 16);
}

// ---------------------------------------------------------------------------
// Beta logits GEMM via split-bf16 MFMA (ahbh + ahbl + albh ~ f32 accuracy).
// 512 threads (8 waves, 2x4), BM=BN=128, BK=64, register-prefetch pipeline
// (issue next tile's global loads before MFMA, ds_write after the barrier).
// XOR-swizzled LDS (proven 0 bank conflicts). Flat grid with bijective
// XCD-chunked, M-major decode so the 20 M-blocks sharing an emb tile run
// consecutively on one XCD (L2 reuse).
// Epilogue: exp(logit) store + per-row sum atomics (softmax w/o max;
// logits are O(0.3)).
// ---------------------------------------------------------------------------
__global__ __launch_bounds__(512, 4) void gemm_beta(
    const short* __restrict__ Ah, const short* __restrict__ Al,
    const float* __restrict__ Bf,   // emb [30000,300]
    float* __restrict__ Cexp,       // o_beta gets exp(logit)
    float* __restrict__ bsum)       // [2500] zeroed
{
    __shared__ __align__(16) short lds[4 * 8192];  // Ah,Al,Bh,Bl tiles (16KB each)
    const int tid = threadIdx.x;
    const int lane = tid & 63;
    const int w = tid >> 6;            // 0..7
    const int wr = w >> 2, wc = w & 3; // 2 x 4 wave grid
    const int l15 = lane & 15, l4 = lane >> 4;

    // bijective XCD-chunked decode (m204), M-major within each XCD
    const int NM = MPAD_ / 128;                 // 20
    const int nwg = (NPAD_ / 128) * NM;         // 4700
    const int qq_ = nwg / 8, rr_ = nwg % 8;
    int orig = blockIdx.x;
    int xcd = orig & 7, ixc = orig >> 3;
    int wg = (xcd < rr_ ? xcd * (qq_ + 1) : rr_ * (qq_ + 1) + (xcd - rr_) * qq_) + ixc;
    const int bn = (wg / NM) * 128;
    const int bm = (wg % NM) * 128;

    f32x4 acc[4][2];
#pragma unroll
    for (int mi = 0; mi < 4; ++mi)
#pragma unroll
        for (int ni = 0; ni < 2; ++ni) acc[mi][ni] = (f32x4){0.f, 0.f, 0.f, 0.f};

    uint4  va[4];     // prefetched A hi/lo chunks
    float4 vb[4];     // prefetched raw B f32

    // ---- load tile k0 into registers ----
    auto loadTile = [&](int k0) {
#pragma unroll
        for (int q = 0; q < 4; ++q) {
            int L = q * 512 + tid;
            int tile = L >> 10;            // 0=Ah, 1=Al
            int c = L & 1023;
            int r = c >> 3;
            int k8 = (c & 7) ^ (r & 7);
            const short* src = (tile ? Al : Ah) + (size_t)(bm + r) * KP_ + k0 + k8 * 8;
            va[q] = *(const uint4*)src;
        }
#pragma unroll
        for (int q = 0; q < 2; ++q) {
            int L = q * 512 + tid;
            int r = L >> 3;
            int k8 = (L & 7) ^ (r & 7);
            int rg = bn + r;
            int kb = k0 + k8 * 8;
            float4 u0, u1;
            if (rg < V_ && kb + 8 <= E_) {
                u0 = *(const float4*)(Bf + (size_t)rg * E_ + kb);
                u1 = *(const float4*)(Bf + (size_t)rg * E_ + kb + 4);
            } else {
                float t[8];
#pragma unroll
                for (int e = 0; e < 8; ++e) {
                    int kk = kb + e;
                    t[e] = (rg < V_ && kk < E_) ? Bf[(size_t)rg * E_ + kk] : 0.f;
                }
                u0.x = t[0]; u0.y = t[1]; u0.z = t[2]; u0.w = t[3];
                u1.x = t[4]; u1.y = t[5]; u1.z = t[6]; u1.w = t[7];
            }
            vb[q * 2] = u0; vb[q * 2 + 1] = u1;
        }
    };
    // ---- write registers to LDS (with B f32 -> bf16 hi/lo split) ----
    auto writeTile = [&]() {
#pragma unroll
        for (int q = 0; q < 4; ++q) {
            int L = q * 512 + tid;
            int tile = L >> 10;
            int c = L & 1023;
            *(uint4*)&lds[(size_t)(tile * 1024 + c) * 8] = va[q];
        }
#pragma unroll
        for (int q = 0; q < 2; ++q) {
            int L = q * 512 + tid;
            float vv[8];
            float4 u0 = vb[q * 2], u1 = vb[q * 2 + 1];
            vv[0] = u0.x; vv[1] = u0.y; vv[2] = u0.z; vv[3] = u0.w;
            vv[4] = u1.x; vv[5] = u1.y; vv[6] = u1.z; vv[7] = u1.w;
            unsigned int hpk[4], lpk[4];
#pragma unroll
            for (int e = 0; e < 8; e += 2) {
                unsigned int b0 = __float_as_uint(vv[e]);
                unsigned int b1 = __float_as_uint(vv[e + 1]);
                hpk[e >> 1] = (b0 >> 16) | (b1 & 0xFFFF0000u);
                float d0 = vv[e]     - __uint_as_float(b0 & 0xFFFF0000u);
                float d1 = vv[e + 1] - __uint_as_float(b1 & 0xFFFF0000u);
                lpk[e >> 1] = (__float_as_uint(d0) >> 16) | (__float_as_uint(d1) & 0xFFFF0000u);
            }
            uint4 hv; hv.x = hpk[0]; hv.y = hpk[1]; hv.z = hpk[2]; hv.w = hpk[3];
            uint4 lv; lv.x = lpk[0]; lv.y = lpk[1]; lv.z = lpk[2]; lv.w = lpk[3];
            *(uint4*)&lds[(size_t)(2048 + L) * 8] = hv;
            *(uint4*)&lds[(size_t)(3072 + L) * 8] = lv;
        }
    };

    loadTile(0);
    writeTile();
    __syncthreads();

    for (int k0 = 0; k0 < KP_; k0 += 64) {
        const bool nxt = (k0 + 64) < KP_;
        if (nxt) loadTile(k0 + 64);   // overlap with MFMA below

#pragma unroll
        for (int ks = 0; ks < 2; ++ks) {
            bf16x8 fbh[2], fbl[2];
#pragma unroll
            for (int ni = 0; ni < 2; ++ni) {
                int r = wc * 32 + ni * 16 + l15;
                int s = r * 8 + ((ks * 4 + l4) ^ (r & 7));
                fbh[ni] = *(const bf16x8*)&lds[(size_t)(2048 + s) * 8];
                fbl[ni] = *(const bf16x8*)&lds[(size_t)(3072 + s) * 8];
            }
#pragma unroll
            for (int mi = 0; mi < 4; ++mi) {
                int r = wr * 64 + mi * 16 + l15;
                int s = r * 8 + ((ks * 4 + l4) ^ (r & 7));
                bf16x8 fah = *(const bf16x8*)&lds[(size_t)s * 8];
                bf16x8 fal = *(const bf16x8*)&lds[(size_t)(1024 + s) * 8];
#pragma unroll
                for (int ni = 0; ni < 2; ++ni) {
                    acc[mi][ni] = __builtin_amdgcn_mfma_f32_16x16x32_bf16(
                        fah, fbh[ni], acc[mi][ni], 0, 0, 0);
                    acc[mi][ni] = __builtin_amdgcn_mfma_f32_16x16x32_bf16(
                        fah, fbl[ni], acc[mi][ni], 0, 0, 0);
                    acc[mi][ni] = __builtin_amdgcn_mfma_f32_16x16x32_bf16(
                        fal, fbh[ni], acc[mi][ni], 0, 0, 0);
                }
            }
        }
        __syncthreads();
        if (nxt) {
            writeTile();
            __syncthreads();
        }
    }

    // ---- epilogue: exp, store, per-row sum (C/D: col=lane&15, row=(lane>>4)*4+reg)
#pragma unroll
    for (int mi = 0; mi < 4; ++mi) {
#pragma unroll
        for (int reg = 0; reg < 4; ++reg) {
            int grow = bm + wr * 64 + mi * 16 + (l4 << 2) + reg;
            float rs = 0.f;
            float ex[2];
#pragma unroll
            for (int ni = 0; ni < 2; ++ni) {
                int gcol = bn + wc * 32 + ni * 16 + l15;
                float e = (gcol < V_) ? __expf(acc[mi][ni][reg]) : 0.f;
                ex[ni] = e;
                rs += e;
            }
            if (grow < T_ * K_) {
#pragma unroll
                for (int ni = 0; ni < 2; ++ni) {
                    int gcol = bn + wc * 32 + ni * 16 + l15;
                    if (gcol < V_) Cexp[(size_t)grow * V_ + gcol] = ex[ni];
                }
            }
            rs += __shfl_xor(rs, 1);
            rs += __shfl_xor(rs, 2);
            rs += __shfl_xor(rs, 4);
            rs += __shfl_xor(rs, 8);
            if (l15 == 0 && grow < T_ * K_) atomicAdd(&bsum[grow], rs);
        }
    }
}

// ---------------------------------------------------------------------------
// beta[row][:] *= 1/bsum[row]  (softmax normalization), grid-stride.
// ---------------------------------------------------------------------------
__global__ __launch_bounds__(256) void beta_scale(
    float* __restrict__ beta, const float* __restrict__ bsum)
{
    const int total4 = T_ * K_ * (V_ / 4);
    for (int i = blockIdx.x * 256 + threadIdx.x; i < total4; i += gridDim.x * 256) {
        int row = i / (V_ / 4);
        float inv = 1.f / bsum[row];
        float4 v = ((const float4*)beta)[i];
        v.x *= inv; v.y *= inv; v.z *= inv; v.w *= inv;
        ((float4*)beta)[i] = v;
    }
}

// ---------------------------------------------------------------------------
// px / lnpx / nll accumulation. Grid (v-chunks, t). beta[t] staged in LDS.
// ---------------------------------------------------------------------------
__global__ __launch_bounds__(256) void px_kernel(
    const float* __restrict__ beta, const float* __restrict__ theta,
    const int* __restrict__ ts, const float* __restrict__ X,
    float* __restrict__ lnpx, float* __restrict__ nll_acc)
{
    __shared__ float sb[K_][256];
    int t = blockIdx.y;
    int tid = threadIdx.x;
    int v = blockIdx.x * 256 + tid;
    bool vok = v < V_;
    bool any = false;
    for (int b = 0; b < B_; ++b) any |= (ts[b] == t);
    if (!any) return;
    for (int k = 0; k < K_; ++k)
        sb[k][tid] = vok ? beta[((size_t)t * K_ + k) * V_ + v] : 0.f;
    __syncthreads();
    float acc = 0.f;
    for (int b = 0; b < B_; ++b) {
        if (ts[b] != t) continue;
        const float* th = theta + b * K_;
        float px = 0.f;
#pragma unroll
        for (int k = 0; k < K_; ++k) px += th[k] * sb[k][tid];
        float l = logf(px + 1e-6f);
        if (vok) {
            lnpx[(size_t)b * V_ + v] = l;
            acc += l * X[(size_t)b * V_ + v];
        }
    }
    for (int off = 32; off; off >>= 1) acc += __shfl_down(acc, off);
    __shared__ float red[4];
    int wid = tid >> 6, lane = tid & 63;
    if (lane == 0) red[wid] = acc;
    __syncthreads();
    if (tid == 0) atomicAdd(nll_acc, red[0] + red[1] + red[2] + red[3]);
}

// ---------------------------------------------------------------------------
// kl_alpha reduction over (K,T,E) in mu_q_alpha's native layout.
// ---------------------------------------------------------------------------
__global__ __launch_bounds__(256) void kl_alpha_kernel(
    const float* __restrict__ mu, const float* __restrict__ lsig,
    float* __restrict__ out)
{
    int idx = blockIdx.x * 256 + threadIdx.x;
    float term = 0.f;
    if (idx < K_ * T_ * E_) {
        int r = idx % (T_ * E_);
        int t = r / E_;
        float a = mu[idx];
        float q = lsig[idx];
        float pmu = (t > 0) ? mu[idx - E_] : 0.f;
        float pls = (t > 0) ? LOGD_ : 0.f;
        float d = a - pmu;
        term = 0.5f * ((expf(q) + d * d) / (expf(pls) + 1e-6f) - 1.f + pls - q);
    }
    for (int off = 32; off; off >>= 1) term += __shfl_down(term, off);
    __shared__ float red[4];
    int wid = threadIdx.x >> 6, lane = threadIdx.x & 63;
    if (lane == 0) red[wid] = term;
    __syncthreads();
    if (threadIdx.x == 0) atomicAdd(out, red[0] + red[1] + red[2] + red[3]);
}

__global__ void finalize_nll(const float* __restrict__ acc, float* __restrict__ out)
{
    *out = -acc[0] * (1.f / (float)B_);
}

// ---------------------------------------------------------------------------
extern "C" void kernel_launch(void* const* d_in, const int* in_sizes, int n_in,
                              void* d_out, int out_size, void* d_ws, size_t ws_size,
                              hipStream_t stream)
{
    const float* X          = (const float*)d_in[0];
    const int*   ts         = (const int*)d_in[1];
    const float* X_mean     = (const float*)d_in[2];
    const float* W_eta_map  = (const float*)d_in[3];
    const float* b_eta_map  = (const float*)d_in[4];
    const float* lstm_Wih   = (const float*)d_in[5];
    const float* lstm_Whh   = (const float*)d_in[6];
    const float* lstm_bih   = (const float*)d_in[7];
    const float* lstm_bhh   = (const float*)d_in[8];
    const float* W_qeta_mu  = (const float*)d_in[9];
    const float* b_qeta_mu  = (const float*)d_in[10];
    const float* W_qeta_ls  = (const float*)d_in[11];
    const float* b_qeta_ls  = (const float*)d_in[12];
    const float* W1         = (const float*)d_in[13];
    const float* b1         = (const float*)d_in[14];
    const float* W2         = (const float*)d_in[15];
    const float* b2         = (const float*)d_in[16];
    const float* W_qt_mu    = (const float*)d_in[17];
    const float* b_qt_mu    = (const float*)d_in[18];
    const float* W_qt_ls    = (const float*)d_in[19];
    const float* b_qt_ls    = (const float*)d_in[20];
    const float* mu_q_alpha = (const float*)d_in[21];
    const float* ls_q_alpha = (const float*)d_in[22];
    const float* emb        = (const float*)d_in[23];

    float* out     = (float*)d_out;
    float* o_theta = out;                          // [B,K]
    float* o_lnpx  = out + (size_t)B_ * K_;        // [B,V]
    float* o_beta  = o_lnpx + (size_t)B_ * V_;     // [T,K,V]
    float* o_scal  = o_beta + (size_t)T_ * K_ * V_; // nll, kl_alpha, kl_eta, kl_theta

    float* ws = (float*)d_ws;
    float* w_inv   = ws;               // 128
    float* w_rnn   = ws + 128;         // 12800
    float* w_seq0  = ws + 12928;       // 12800  (final LSTM layer out)
    float* w_houtA = ws + 38528;       // 12800  (layer-0 out)
    float* w_houtB = ws + 51328;       // 12800  (layer-1 out)
    float* w_hping = ws + 64128;       // 512
    float* w_barc  = ws + 64640;       // 1 (int)
    float* w_etas  = ws + 89728;       // 2500
    float* w_h1    = ws + 92228;       // 102400
    float* w_h2    = ws + 194628;      // 102400
    float* w_mu    = ws + 297028;      // 6400
    float* w_ls    = ws + 303428;      // 6400
    float* w_nll   = ws + 309828;      // 1
    float* w_bsum  = ws + 309832;      // 2500 (+pad to 312344)
    short* w_Ah    = (short*)(ws + 312344);   // 819200 shorts
    short* w_Al    = (short*)(ws + 721944);   // 819200 shorts

    // zero accumulators (d_out / d_ws are poisoned before every launch)
    hipMemsetAsync(o_scal, 0, 4 * sizeof(float), stream);
    hipMemsetAsync(w_h1, 0, (size_t)(102400 + 102400 + 6400 + 6400 + 1) * sizeof(float), stream);
    hipMemsetAsync(w_rnn, 0, (size_t)T_ * HE_ * sizeof(float), stream);
    hipMemsetAsync(w_barc, 0, sizeof(int), stream);
    hipMemsetAsync(w_bsum, 0, (size_t)T_ * K_ * sizeof(float), stream);

    rowsum_inv<<<B_, 256, 0, stream>>>(X, w_inv);

    // rnn_in = X_mean @ W_eta_map^T + b_eta_map   [T,HE], split-K 125x240
    gemm_nt<<<dim3(HE_ / TN, 1, 125), 256, 0, stream>>>(
        X_mean, V_, T_, W_eta_map, V_, HE_, V_, w_rnn, HE_, nullptr, 3, 240);
    bias_act<<<(T_ * HE_ + 255) / 256, 256, 0, stream>>>(
        w_rnn, b_eta_map, T_ * HE_, HE_, 2);

    // fused 3-layer LSTM (input projection fused; grid-barrier per step)
    lstm_all<<<NLB, 256, 0, stream>>>(
        w_rnn, lstm_Wih, lstm_Whh, lstm_bih, lstm_bhh,
        w_houtA, w_houtB, w_seq0, w_hping, (int*)w_barc);

    // eta recurrence + kl_eta
    eta_scan<<<1, 256, 0, stream>>>(w_seq0, W_qeta_mu, b_qeta_mu,
                                    W_qeta_ls, b_qeta_ls, w_etas, o_scal + 2);

    // C1 = X @ W1[:, :V]^T, split-K 75x400; epilogue folds rowsum/eta/bias/tanh
    gemm_nt<<<dim3((TH_ + TN - 1) / TN, (B_ + TM - 1) / TM, 75), 256, 0, stream>>>(
        X, V_, B_, W1, V_ + K_, TH_, V_, w_h1, TH_, nullptr, 3, 400);
    h1_epilogue<<<(B_ * TH_ + 255) / 256, 256, 0, stream>>>(
        w_h1, w_inv, w_etas, ts, W1, b1, w_h1);

    // h2 = tanh(h1 @ W2^T + b2), split-K 10x80
    gemm_nt<<<dim3((TH_ + TN - 1) / TN, (B_ + TM - 1) / TM, 10), 256, 0, stream>>>(
        w_h1, TH_, B_, W2, TH_, TH_, TH_, w_h2, TH_, nullptr, 3, 80);
    bias_act<<<(B_ * TH_ + 255) / 256, 256, 0, stream>>>(
        w_h2, b2, B_ * TH_, TH_, 1);

    // mu_t / ls_t: K=800, split-K 25x32
    gemm_nt<<<dim3(1, (B_ + TM - 1) / TM, 25), 256, 0, stream>>>(
        w_h2, TH_, B_, W_qt_mu, TH_, K_, TH_, w_mu, K_, nullptr, 3, 32);
    gemm_nt<<<dim3(1, (B_ + TM - 1) / TM, 25), 256, 0, stream>>>(
        w_h2, TH_, B_, W_qt_ls, TH_, K_, TH_, w_ls, K_, nullptr, 3, 32);
    bias_act<<<(B_ * K_ + 255) / 256, 256, 0, stream>>>(
        w_mu, b_qt_mu, B_ * K_, K_, 2);
    bias_act<<<(B_ * K_ + 255) / 256, 256, 0, stream>>>(
        w_ls, b_qt_ls, B_ * K_, K_, 2);

    theta_kernel<<<B_, 64, 0, stream>>>(w_mu, w_ls, w_etas, ts, o_theta, o_scal + 3);

    // beta: alpha transpose+split, split-bf16 MFMA GEMM with fused exp/rowsum,
    // then normalize in place
    conv_alpha<<<(MPAD_ * KP_ + 255) / 256, 256, 0, stream>>>(mu_q_alpha, w_Ah, w_Al);
    gemm_beta<<<(NPAD_ / 128) * (MPAD_ / 128), 512, 0, stream>>>(
        w_Ah, w_Al, emb, o_beta, w_bsum);
    beta_scale<<<2048, 256, 0, stream>>>(o_beta, w_bsum);

    // px / lnpx / nll
    px_kernel<<<dim3((V_ + 255) / 256, T_), 256, 0, stream>>>(
        o_beta, o_theta, ts, X, o_lnpx, w_nll);

    kl_alpha_kernel<<<(K_ * T_ * E_ + 255) / 256, 256, 0, stream>>>(
        mu_q_alpha, ls_q_alpha, o_scal + 1);

    finalize_nll<<<1, 1, 0, stream>>>(w_nll, o_scal);
}

// Round 5
// 2239.030 us; speedup vs baseline: 1.2353x; 1.1489x over previous
//
#include <hip/hip_runtime.h>
#include <math.h>

// Problem constants
#define B_  128
#define V_  30000
#define T_  50
#define K_  50
#define HE_ 256
#define TH_ 800
#define E_  300
#define L_  3

#define LOGD_ (-5.2983173665480363f)   // log(0.005) in f32

typedef short bf16x8 __attribute__((ext_vector_type(8)));
typedef float f32x4  __attribute__((ext_vector_type(4)));

// ---------------------------------------------------------------------------
// Generic f32 NT GEMM: C[M,N] = A[M,K] * B[N,K]^T  (A,B row-major, K contiguous)
// mode: 0 = plain store, 1 = tanh(x + bias[col]), 2 = x + bias[col]
//       3 = split-K atomic accumulate (C must be pre-zeroed; bias ignored)
// Used only for the small K=800 GEMMs (h2, mu_t, ls_t).
// ---------------------------------------------------------------------------
#define TM 64
#define TN 64
#define TK 16

__global__ __launch_bounds__(256) void gemm_nt(
    const float* __restrict__ A, int lda, int M,
    const float* __restrict__ B, int ldb, int N,
    int K,
    float* __restrict__ C, int ldc,
    const float* __restrict__ bias, int mode, int kchunk)
{
    __shared__ float As[TK][TM + 4];
    __shared__ float Bs[TK][TN + 4];
    const int tid = threadIdx.x;
    const int bm = blockIdx.y * TM;
    const int bn = blockIdx.x * TN;
    const int tx = tid & 15;       // 0..15 col group
    const int ty = tid >> 4;       // 0..15 row group
    const int lr = tid >> 2;       // 0..63 tile row for loads
    const int lc = (tid & 3) << 2; // 0,4,8,12 k offset for loads

    float acc[4][4];
#pragma unroll
    for (int i = 0; i < 4; ++i)
#pragma unroll
        for (int j = 0; j < 4; ++j) acc[i][j] = 0.f;

    const int kbeg = blockIdx.z * kchunk;
    const int kend = min(K, kbeg + kchunk);

    for (int k0 = kbeg; k0 < kend; k0 += TK) {
        {
            float v0 = 0.f, v1 = 0.f, v2 = 0.f, v3 = 0.f;
            int gr = bm + lr;
            if (gr < M) {
                const float* p = A + (size_t)gr * lda + k0 + lc;
                int rem = K - (k0 + lc);
                if (rem >= 4) {
                    float2 a0 = *(const float2*)p;
                    float2 a1 = *(const float2*)(p + 2);
                    v0 = a0.x; v1 = a0.y; v2 = a1.x; v3 = a1.y;
                } else {
                    if (rem > 0) v0 = p[0];
                    if (rem > 1) v1 = p[1];
                    if (rem > 2) v2 = p[2];
                }
            }
            As[lc + 0][lr] = v0; As[lc + 1][lr] = v1;
            As[lc + 2][lr] = v2; As[lc + 3][lr] = v3;
        }
        {
            float v0 = 0.f, v1 = 0.f, v2 = 0.f, v3 = 0.f;
            int gr = bn + lr;
            if (gr < N) {
                const float* p = B + (size_t)gr * ldb + k0 + lc;
                int rem = K - (k0 + lc);
                if (rem >= 4) {
                    float2 a0 = *(const float2*)p;
                    float2 a1 = *(const float2*)(p + 2);
                    v0 = a0.x; v1 = a0.y; v2 = a1.x; v3 = a1.y;
                } else {
                    if (rem > 0) v0 = p[0];
                    if (rem > 1) v1 = p[1];
                    if (rem > 2) v2 = p[2];
                }
            }
            Bs[lc + 0][lr] = v0; Bs[lc + 1][lr] = v1;
            Bs[lc + 2][lr] = v2; Bs[lc + 3][lr] = v3;
        }
        __syncthreads();
#pragma unroll
        for (int kk = 0; kk < TK; ++kk) {
            float a[4], b[4];
#pragma unroll
            for (int i = 0; i < 4; ++i) a[i] = As[kk][ty * 4 + i];
#pragma unroll
            for (int j = 0; j < 4; ++j) b[j] = Bs[kk][tx * 4 + j];
#pragma unroll
            for (int i = 0; i < 4; ++i)
#pragma unroll
                for (int j = 0; j < 4; ++j) acc[i][j] += a[i] * b[j];
        }
        __syncthreads();
    }

#pragma unroll
    for (int i = 0; i < 4; ++i) {
        int row = bm + ty * 4 + i;
        if (row >= M) continue;
#pragma unroll
        for (int j = 0; j < 4; ++j) {
            int col = bn + tx * 4 + j;
            if (col >= N) continue;
            float v = acc[i][j];
            if (mode == 3) {
                atomicAdd(&C[(size_t)row * ldc + col], v);
            } else {
                if (mode == 1) v = tanhf(v + bias[col]);
                else if (mode == 2) v = v + bias[col];
                C[(size_t)row * ldc + col] = v;
            }
        }
    }
}

// ---------------------------------------------------------------------------
// Split-bf16 3-MFMA NT GEMM with split-K atomic accumulation.
// C[M,N] += A[M,K]*B[N,K]^T, A/B f32 in HBM, converted to bf16 hi/lo during
// LDS staging (ahbh + ahbl + albh ~ f32 accuracy). Same proven structure as
// gemm_beta: 512 threads (2x4 waves), BM=BN=128, BK=64, XOR-swizzled LDS,
// register-prefetch pipeline. grid = (N/128, M/128, z); kchunk % 64 == 0.
// C must be pre-zeroed.
// ---------------------------------------------------------------------------
__global__ __launch_bounds__(512, 4) void gemm_bf3(
    const float* __restrict__ A, int lda, int M,
    const float* __restrict__ B, int ldb, int N,
    int K,
    float* __restrict__ C, int ldc, int kchunk)
{
    __shared__ __align__(16) short lds[4 * 8192];  // Ah,Al,Bh,Bl tiles
    const int tid = threadIdx.x;
    const int lane = tid & 63;
    const int w = tid >> 6;
    const int wr = w >> 2, wc = w & 3;
    const int l15 = lane & 15, l4 = lane >> 4;
    const int bm = blockIdx.y * 128;
    const int bn = blockIdx.x * 128;
    const int kbeg = blockIdx.z * kchunk;
    const int kend = kbeg + kchunk;

    f32x4 acc[4][2];
#pragma unroll
    for (int mi = 0; mi < 4; ++mi)
#pragma unroll
        for (int ni = 0; ni < 2; ++ni) acc[mi][ni] = (f32x4){0.f, 0.f, 0.f, 0.f};

    float4 va[4], vb[4];

    auto loadSide = [&](const float* __restrict__ P, int ldp, int Rlim,
                        int base, int k0, float4* dst) {
#pragma unroll
        for (int q = 0; q < 2; ++q) {
            int L = q * 512 + tid;
            int r = L >> 3;
            int k8 = (L & 7) ^ (r & 7);
            int rg = base + r;
            int kb = k0 + k8 * 8;
            float4 u0, u1;
            if (rg < Rlim && kb + 8 <= K) {
                u0 = *(const float4*)(P + (size_t)rg * ldp + kb);
                u1 = *(const float4*)(P + (size_t)rg * ldp + kb + 4);
            } else {
                float tt[8];
#pragma unroll
                for (int e = 0; e < 8; ++e) {
                    int kk = kb + e;
                    tt[e] = (rg < Rlim && kk < K) ? P[(size_t)rg * ldp + kk] : 0.f;
                }
                u0.x = tt[0]; u0.y = tt[1]; u0.z = tt[2]; u0.w = tt[3];
                u1.x = tt[4]; u1.y = tt[5]; u1.z = tt[6]; u1.w = tt[7];
            }
            dst[q * 2] = u0; dst[q * 2 + 1] = u1;
        }
    };
    auto writeSide = [&](const float4* src, int tbase) {
#pragma unroll
        for (int q = 0; q < 2; ++q) {
            int L = q * 512 + tid;
            float vv[8];
            float4 u0 = src[q * 2], u1 = src[q * 2 + 1];
            vv[0] = u0.x; vv[1] = u0.y; vv[2] = u0.z; vv[3] = u0.w;
            vv[4] = u1.x; vv[5] = u1.y; vv[6] = u1.z; vv[7] = u1.w;
            unsigned int hpk[4], lpk[4];
#pragma unroll
            for (int e = 0; e < 8; e += 2) {
                unsigned int b0 = __float_as_uint(vv[e]);
                unsigned int b1 = __float_as_uint(vv[e + 1]);
                hpk[e >> 1] = (b0 >> 16) | (b1 & 0xFFFF0000u);
                float d0 = vv[e]     - __uint_as_float(b0 & 0xFFFF0000u);
                float d1 = vv[e + 1] - __uint_as_float(b1 & 0xFFFF0000u);
                lpk[e >> 1] = (__float_as_uint(d0) >> 16) | (__float_as_uint(d1) & 0xFFFF0000u);
            }
            uint4 hv; hv.x = hpk[0]; hv.y = hpk[1]; hv.z = hpk[2]; hv.w = hpk[3];
            uint4 lv; lv.x = lpk[0]; lv.y = lpk[1]; lv.z = lpk[2]; lv.w = lpk[3];
            *(uint4*)&lds[(size_t)(tbase + L) * 8] = hv;
            *(uint4*)&lds[(size_t)(tbase + 1024 + L) * 8] = lv;
        }
    };

    loadSide(A, lda, M, bm, kbeg, va);
    loadSide(B, ldb, N, bn, kbeg, vb);
    writeSide(va, 0);
    writeSide(vb, 2048);
    __syncthreads();

    for (int k0 = kbeg; k0 < kend; k0 += 64) {
        const bool nxt = (k0 + 64) < kend;
        if (nxt) {
            loadSide(A, lda, M, bm, k0 + 64, va);
            loadSide(B, ldb, N, bn, k0 + 64, vb);
        }
#pragma unroll
        for (int ks = 0; ks < 2; ++ks) {
            bf16x8 fbh[2], fbl[2];
#pragma unroll
            for (int ni = 0; ni < 2; ++ni) {
                int r = wc * 32 + ni * 16 + l15;
                int s = r * 8 + ((ks * 4 + l4) ^ (r & 7));
                fbh[ni] = *(const bf16x8*)&lds[(size_t)(2048 + s) * 8];
                fbl[ni] = *(const bf16x8*)&lds[(size_t)(3072 + s) * 8];
            }
#pragma unroll
            for (int mi = 0; mi < 4; ++mi) {
                int r = wr * 64 + mi * 16 + l15;
                int s = r * 8 + ((ks * 4 + l4) ^ (r & 7));
                bf16x8 fah = *(const bf16x8*)&lds[(size_t)s * 8];
                bf16x8 fal = *(const bf16x8*)&lds[(size_t)(1024 + s) * 8];
#pragma unroll
                for (int ni = 0; ni < 2; ++ni) {
                    acc[mi][ni] = __builtin_amdgcn_mfma_f32_16x16x32_bf16(
                        fah, fbh[ni], acc[mi][ni], 0, 0, 0);
                    acc[mi][ni] = __builtin_amdgcn_mfma_f32_16x16x32_bf16(
                        fah, fbl[ni], acc[mi][ni], 0, 0, 0);
                    acc[mi][ni] = __builtin_amdgcn_mfma_f32_16x16x32_bf16(
                        fal, fbh[ni], acc[mi][ni], 0, 0, 0);
                }
            }
        }
        __syncthreads();
        if (nxt) {
            writeSide(va, 0);
            writeSide(vb, 2048);
            __syncthreads();
        }
    }

    // epilogue: split-K atomic accumulate
#pragma unroll
    for (int mi = 0; mi < 4; ++mi) {
#pragma unroll
        for (int reg = 0; reg < 4; ++reg) {
            int grow = bm + wr * 64 + mi * 16 + (l4 << 2) + reg;
            if (grow >= M) continue;
#pragma unroll
            for (int ni = 0; ni < 2; ++ni) {
                int gcol = bn + wc * 32 + ni * 16 + l15;
                if (gcol < N) atomicAdd(&C[(size_t)grow * ldc + gcol], acc[mi][ni][reg]);
            }
        }
    }
}

// ---------------------------------------------------------------------------
// Epilogue for split-K GEMMs: C[i] = (tanh)(C[i] + bias[col]).
// ---------------------------------------------------------------------------
__global__ __launch_bounds__(256) void bias_act(
    float* __restrict__ C, const float* __restrict__ bias,
    int total, int N, int mode)
{
    int idx = blockIdx.x * 256 + threadIdx.x;
    if (idx >= total) return;
    int j = idx % N;
    float v = C[idx] + bias[j];
    if (mode == 1) v = tanhf(v);
    C[idx] = v;
}

// ---------------------------------------------------------------------------
// Row sums of X -> 1/sum
// ---------------------------------------------------------------------------
__global__ __launch_bounds__(256) void rowsum_inv(const float* __restrict__ X,
                                                  float* __restrict__ inv)
{
    int b = blockIdx.x;
    const float4* p = (const float4*)(X + (size_t)b * V_);
    float s = 0.f;
    for (int i = threadIdx.x; i < V_ / 4; i += 256) {
        float4 v = p[i];
        s += v.x + v.y + v.z + v.w;
    }
    for (int off = 32; off; off >>= 1) s += __shfl_down(s, off);
    __shared__ float red[4];
    int wid = threadIdx.x >> 6, lane = threadIdx.x & 63;
    if (lane == 0) red[wid] = s;
    __syncthreads();
    if (threadIdx.x == 0) inv[b] = 1.f / (red[0] + red[1] + red[2] + red[3]);
}

// ---------------------------------------------------------------------------
// Wavefront-pipelined 3-layer LSTM. 3 layer-groups x GLB blocks run
// concurrently; layer l step t waits on cnt[l-1] >= (t+1)*GLB (input ready)
// and cnt[l] >= t*GLB (own h_{t-1} complete). No global barrier; critical
// path = (T + 2) steps instead of 3T. Weights live in VGPRs (64 gate rows
// per block, 4 threads/row, 128 weight floats per thread).
// ---------------------------------------------------------------------------
#define GLB 16

__global__ __launch_bounds__(256, 1) void lstm_pipe(
    const float* __restrict__ rnn_in,   // [T,HE] layer-0 input
    const float* __restrict__ Wih,      // [L,4HE,HE]
    const float* __restrict__ Whh,      // [L,4HE,HE]
    const float* __restrict__ bih,      // [L,4HE]
    const float* __restrict__ bhh,      // [L,4HE]
    float* __restrict__ houtA,          // [T,HE] layer-0 out
    float* __restrict__ houtB,          // [T,HE] layer-1 out
    float* __restrict__ houtF,          // [T,HE] layer-2 out (final)
    int* __restrict__ cnts)             // 3 counters, 32 ints apart, zeroed
{
    __shared__ __align__(16) float sx[HE_];
    __shared__ __align__(16) float sh[HE_];
    __shared__ float sg[64];
    const int tid = threadIdx.x;
    const int l   = blockIdx.x / GLB;
    const int blk = blockIdx.x % GLB;
    const int row_local = tid >> 2;        // 0..63
    const int chunk = tid & 3;             // 0..3
    const int gate = row_local >> 4;       // 0..3 (i,f,g,o)
    const int jloc = row_local & 15;       // 0..15
    const int gr = gate * HE_ + blk * 16 + jloc;  // gate row 0..1023

    // preload this thread's weight slices (cols [chunk*64, chunk*64+64))
    float4 wih[16], whh[16];
    const float4* pi = (const float4*)(Wih + ((size_t)l * 4 * HE_ + gr) * HE_ + chunk * 64);
    const float4* pw = (const float4*)(Whh + ((size_t)l * 4 * HE_ + gr) * HE_ + chunk * 64);
#pragma unroll
    for (int q = 0; q < 16; ++q) { wih[q] = pi[q]; whh[q] = pw[q]; }
    const float bias = bih[l * 4 * HE_ + gr] + bhh[l * 4 * HE_ + gr];

    const float* xs = (l == 0) ? rnn_in : ((l == 1) ? houtA : houtB);
    float* hd = (l == 0) ? houtA : ((l == 1) ? houtB : houtF);
    int* cin  = cnts + (l - 1) * 32;
    int* cown = cnts + l * 32;

    float cst = 0.f;
    for (int t = 0; t < T_; ++t) {
        // wait for input x_t (layer l-1 done with step t) and own h_{t-1}
        if (tid == 0) {
            if (l > 0) {
                const int tgt = (t + 1) * GLB;
                while (__hip_atomic_load(cin, __ATOMIC_ACQUIRE, __HIP_MEMORY_SCOPE_AGENT) < tgt)
                    __builtin_amdgcn_s_sleep(1);
            }
            if (t > 0) {
                const int tgt = t * GLB;
                while (__hip_atomic_load(cown, __ATOMIC_ACQUIRE, __HIP_MEMORY_SCOPE_AGENT) < tgt)
                    __builtin_amdgcn_s_sleep(1);
            }
        }
        __syncthreads();

        sx[tid] = xs[t * HE_ + tid];
        sh[tid] = (t > 0) ? hd[(t - 1) * HE_ + tid] : 0.f;
        __syncthreads();

        float acc = 0.f;
        const float4* xa = (const float4*)&sx[chunk * 64];
        const float4* ha = (const float4*)&sh[chunk * 64];
#pragma unroll
        for (int q = 0; q < 16; ++q) {
            float4 a = xa[q], b = ha[q];
            float4 wa = wih[q], wc = whh[q];
            acc += wa.x * a.x + wa.y * a.y + wa.z * a.z + wa.w * a.w
                 + wc.x * b.x + wc.y * b.y + wc.z * b.z + wc.w * b.w;
        }
        acc += __shfl_xor(acc, 1);
        acc += __shfl_xor(acc, 2);
        if (chunk == 0) sg[row_local] = acc + bias;
        __syncthreads();

        // gates + publish (wave 0 only: stores then fence then arrive, so the
        // wave-level fence orders the lanes' h stores before the counter bump)
        if (tid < 16) {
            float gi = sg[tid], gf = sg[16 + tid], gg = sg[32 + tid], go = sg[48 + tid];
            float si = 1.f / (1.f + expf(-gi));
            float sf = 1.f / (1.f + expf(-gf));
            float so = 1.f / (1.f + expf(-go));
            cst = sf * cst + si * tanhf(gg);
            float hn = so * tanhf(cst);
            hd[t * HE_ + blk * 16 + tid] = hn;
        }
        if (tid == 0) {
            __threadfence();
            __hip_atomic_fetch_add(cown, 1, __ATOMIC_RELEASE, __HIP_MEMORY_SCOPE_AGENT);
        }
        __syncthreads();
    }
}

// ---------------------------------------------------------------------------
// Sequential eta recurrence, wave-parallel dots: 256 threads, 4 lanes per k.
// ---------------------------------------------------------------------------
__global__ __launch_bounds__(256) void eta_scan(
    const float* __restrict__ rnn_out,  // [T,HE]
    const float* __restrict__ Wmu, const float* __restrict__ bmu,
    const float* __restrict__ Wls, const float* __restrict__ bls,
    float* __restrict__ etas,           // [T,K]
    float* __restrict__ kl_eta_out)
{
    __shared__ float hbuf[HE_ + K_];
    __shared__ float smu[K_];
    __shared__ float red[256];
    const int tid = threadIdx.x;
    const int k = tid >> 2, c = tid & 3;
    if (tid < K_) hbuf[HE_ + tid] = 0.f;
    float kl = 0.f;
    __syncthreads();
    for (int t = 0; t < T_; ++t) {
        if (tid < HE_) hbuf[tid] = rnn_out[t * HE_ + tid];
        __syncthreads();
        if (k < K_) {
            const float* wm = Wmu + k * (HE_ + K_);
            const float* wl = Wls + k * (HE_ + K_);
            float am = 0.f, al = 0.f;
            for (int i = c; i < HE_ + K_; i += 4) {
                float hv = hbuf[i];
                am += wm[i] * hv;
                al += wl[i] * hv;
            }
            am += __shfl_xor(am, 1); am += __shfl_xor(am, 2);
            al += __shfl_xor(al, 1); al += __shfl_xor(al, 2);
            if (c == 0) {
                float mu = am + bmu[k];
                float ls = al + bls[k];
                float eprev = hbuf[HE_ + k];
                float pls = (t == 0) ? 0.f : LOGD_;
                float d = mu - eprev;
                kl += 0.5f * ((expf(ls) + d * d) / (expf(pls) + 1e-6f) - 1.f + pls - ls);
                etas[t * K_ + k] = mu;
                smu[k] = mu;
            }
        }
        __syncthreads();
        if (tid < K_) hbuf[HE_ + tid] = smu[tid];
        __syncthreads();
    }
    red[tid] = kl;
    __syncthreads();
    if (tid == 0) {
        float s = 0.f;
        for (int i = 0; i < 256; ++i) s += red[i];
        *kl_eta_out = s;
    }
}

// ---------------------------------------------------------------------------
// h1 = tanh(inv[b]*C1 + etas[ts[b]]·W1[:,V:] + b1)   (in place on C1)
// ---------------------------------------------------------------------------
__global__ __launch_bounds__(256) void h1_epilogue(
    const float* __restrict__ C1, const float* __restrict__ inv,
    const float* __restrict__ etas, const int* __restrict__ ts,
    const float* __restrict__ W1, const float* __restrict__ b1,
    float* __restrict__ h1)
{
    int idx = blockIdx.x * 256 + threadIdx.x;
    if (idx >= B_ * TH_) return;
    int b = idx / TH_, j = idx % TH_;
    const float* e = etas + ts[b] * K_;
    const float* w = W1 + (size_t)j * (V_ + K_) + V_;
    float s = 0.f;
#pragma unroll
    for (int k = 0; k < K_; ++k) s += e[k] * w[k];
    h1[idx] = tanhf(C1[idx] * inv[b] + s + b1[j]);
}

// ---------------------------------------------------------------------------
// theta = softmax(mu_t) rows; kl_theta accumulated. One block (1 wave) per b.
// ---------------------------------------------------------------------------
__global__ __launch_bounds__(64) void theta_kernel(
    const float* __restrict__ mu_t, const float* __restrict__ ls_t,
    const float* __restrict__ etas, const int* __restrict__ ts,
    float* __restrict__ theta, float* __restrict__ kl_out)
{
    int b = blockIdx.x;
    int lane = threadIdx.x;
    bool ok = lane < K_;
    float m = ok ? mu_t[b * K_ + lane] : -3.4e38f;
    float mx = m;
    for (int off = 32; off; off >>= 1) mx = fmaxf(mx, __shfl_down(mx, off));
    mx = __shfl(mx, 0);
    float e = ok ? expf(m - mx) : 0.f;
    float s = e;
    for (int off = 32; off; off >>= 1) s += __shfl_down(s, off);
    s = __shfl(s, 0);
    if (ok) theta[b * K_ + lane] = e / s;
    float kl = 0.f;
    if (ok) {
        float ls = ls_t[b * K_ + lane];
        float d = m - etas[ts[b] * K_ + lane];
        kl = 0.5f * ((expf(ls) + d * d) / (1.f + 1e-6f) - 1.f - ls);
    }
    for (int off = 32; off; off >>= 1) kl += __shfl_down(kl, off);
    if (lane == 0) atomicAdd(kl_out, kl);
}

// ---------------------------------------------------------------------------
// alpha transpose + bf16 hi/lo split into padded [MPAD,KP] operand.
// ---------------------------------------------------------------------------
#define KP_   320
#define MPAD_ 2560
#define NPAD_ 30080

__global__ __launch_bounds__(256) void conv_alpha(
    const float* __restrict__ mu, short* __restrict__ Ah, short* __restrict__ Al)
{
    int idx = blockIdx.x * 256 + threadIdx.x;
    if (idx >= MPAD_ * KP_) return;
    int row = idx / KP_, e = idx % KP_;
    float v = 0.f;
    if (row < T_ * K_ && e < E_) {
        int t = row / K_, k = row % K_;
        v = mu[((size_t)k * T_ + t) * E_ + e];
    }
    unsigned int u = __float_as_uint(v);
    Ah[idx] = (short)(u >> 16);
    float hf = __uint_as_float(u & 0xFFFF0000u);
    Al[idx] = (short)(__float_as_uint(v - hf) >> 16);
}

// ---------------------------------------------------------------------------
// Beta logits GEMM via split-bf16 MFMA with fused exp + row-sum epilogue.
// ---------------------------------------------------------------------------
__global__ __launch_bounds__(512, 4) void gemm_beta(
    const short* __restrict__ Ah, const short* __restrict__ Al,
    const float* __restrict__ Bf,   // emb [30000,300]
    float* __restrict__ Cexp,       // o_beta gets exp(logit)
    float* __restrict__ bsum)       // [2500] zeroed
{
    __shared__ __align__(16) short lds[4 * 8192];
    const int tid = threadIdx.x;
    const int lane = tid & 63;
    const int w = tid >> 6;
    const int wr = w >> 2, wc = w & 3;
    const int l15 = lane & 15, l4 = lane >> 4;

    const int NM = MPAD_ / 128;
    const int nwg = (NPAD_ / 128) * NM;
    const int qq_ = nwg / 8, rr_ = nwg % 8;
    int orig = blockIdx.x;
    int xcd = orig & 7, ixc = orig >> 3;
    int wg = (xcd < rr_ ? xcd * (qq_ + 1) : rr_ * (qq_ + 1) + (xcd - rr_) * qq_) + ixc;
    const int bn = (wg / NM) * 128;
    const int bm = (wg % NM) * 128;

    f32x4 acc[4][2];
#pragma unroll
    for (int mi = 0; mi < 4; ++mi)
#pragma unroll
        for (int ni = 0; ni < 2; ++ni) acc[mi][ni] = (f32x4){0.f, 0.f, 0.f, 0.f};

    uint4  va[4];
    float4 vb[4];

    auto loadTile = [&](int k0) {
#pragma unroll
        for (int q = 0; q < 4; ++q) {
            int L = q * 512 + tid;
            int tile = L >> 10;
            int c = L & 1023;
            int r = c >> 3;
            int k8 = (c & 7) ^ (r & 7);
            const short* src = (tile ? Al : Ah) + (size_t)(bm + r) * KP_ + k0 + k8 * 8;
            va[q] = *(const uint4*)src;
        }
#pragma unroll
        for (int q = 0; q < 2; ++q) {
            int L = q * 512 + tid;
            int r = L >> 3;
            int k8 = (L & 7) ^ (r & 7);
            int rg = bn + r;
            int kb = k0 + k8 * 8;
            float4 u0, u1;
            if (rg < V_ && kb + 8 <= E_) {
                u0 = *(const float4*)(Bf + (size_t)rg * E_ + kb);
                u1 = *(const float4*)(Bf + (size_t)rg * E_ + kb + 4);
            } else {
                float t[8];
#pragma unroll
                for (int e = 0; e < 8; ++e) {
                    int kk = kb + e;
                    t[e] = (rg < V_ && kk < E_) ? Bf[(size_t)rg * E_ + kk] : 0.f;
                }
                u0.x = t[0]; u0.y = t[1]; u0.z = t[2]; u0.w = t[3];
                u1.x = t[4]; u1.y = t[5]; u1.z = t[6]; u1.w = t[7];
            }
            vb[q * 2] = u0; vb[q * 2 + 1] = u1;
        }
    };
    auto writeTile = [&]() {
#pragma unroll
        for (int q = 0; q < 4; ++q) {
            int L = q * 512 + tid;
            int tile = L >> 10;
            int c = L & 1023;
            *(uint4*)&lds[(size_t)(tile * 1024 + c) * 8] = va[q];
        }
#pragma unroll
        for (int q = 0; q < 2; ++q) {
            int L = q * 512 + tid;
            float vv[8];
            float4 u0 = vb[q * 2], u1 = vb[q * 2 + 1];
            vv[0] = u0.x; vv[1] = u0.y; vv[2] = u0.z; vv[3] = u0.w;
            vv[4] = u1.x; vv[5] = u1.y; vv[6] = u1.z; vv[7] = u1.w;
            unsigned int hpk[4], lpk[4];
#pragma unroll
            for (int e = 0; e < 8; e += 2) {
                unsigned int b0 = __float_as_uint(vv[e]);
                unsigned int b1 = __float_as_uint(vv[e + 1]);
                hpk[e >> 1] = (b0 >> 16) | (b1 & 0xFFFF0000u);
                float d0 = vv[e]     - __uint_as_float(b0 & 0xFFFF0000u);
                float d1 = vv[e + 1] - __uint_as_float(b1 & 0xFFFF0000u);
                lpk[e >> 1] = (__float_as_uint(d0) >> 16) | (__float_as_uint(d1) & 0xFFFF0000u);
            }
            uint4 hv; hv.x = hpk[0]; hv.y = hpk[1]; hv.z = hpk[2]; hv.w = hpk[3];
            uint4 lv; lv.x = lpk[0]; lv.y = lpk[1]; lv.z = lpk[2]; lv.w = lpk[3];
            *(uint4*)&lds[(size_t)(2048 + L) * 8] = hv;
            *(uint4*)&lds[(size_t)(3072 + L) * 8] = lv;
        }
    };

    loadTile(0);
    writeTile();
    __syncthreads();

    for (int k0 = 0; k0 < KP_; k0 += 64) {
        const bool nxt = (k0 + 64) < KP_;
        if (nxt) loadTile(k0 + 64);

#pragma unroll
        for (int ks = 0; ks < 2; ++ks) {
            bf16x8 fbh[2], fbl[2];
#pragma unroll
            for (int ni = 0; ni < 2; ++ni) {
                int r = wc * 32 + ni * 16 + l15;
                int s = r * 8 + ((ks * 4 + l4) ^ (r & 7));
                fbh[ni] = *(const bf16x8*)&lds[(size_t)(2048 + s) * 8];
                fbl[ni] = *(const bf16x8*)&lds[(size_t)(3072 + s) * 8];
            }
#pragma unroll
            for (int mi = 0; mi < 4; ++mi) {
                int r = wr * 64 + mi * 16 + l15;
                int s = r * 8 + ((ks * 4 + l4) ^ (r & 7));
                bf16x8 fah = *(const bf16x8*)&lds[(size_t)s * 8];
                bf16x8 fal = *(const bf16x8*)&lds[(size_t)(1024 + s) * 8];
#pragma unroll
                for (int ni = 0; ni < 2; ++ni) {
                    acc[mi][ni] = __builtin_amdgcn_mfma_f32_16x16x32_bf16(
                        fah, fbh[ni], acc[mi][ni], 0, 0, 0);
                    acc[mi][ni] = __builtin_amdgcn_mfma_f32_16x16x32_bf16(
                        fah, fbl[ni], acc[mi][ni], 0, 0, 0);
                    acc[mi][ni] = __builtin_amdgcn_mfma_f32_16x16x32_bf16(
                        fal, fbh[ni], acc[mi][ni], 0, 0, 0);
                }
            }
        }
        __syncthreads();
        if (nxt) {
            writeTile();
            __syncthreads();
        }
    }

#pragma unroll
    for (int mi = 0; mi < 4; ++mi) {
#pragma unroll
        for (int reg = 0; reg < 4; ++reg) {
            int grow = bm + wr * 64 + mi * 16 + (l4 << 2) + reg;
            float rs = 0.f;
            float ex[2];
#pragma unroll
            for (int ni = 0; ni < 2; ++ni) {
                int gcol = bn + wc * 32 + ni * 16 + l15;
                float e = (gcol < V_) ? __expf(acc[mi][ni][reg]) : 0.f;
                ex[ni] = e;
                rs += e;
            }
            if (grow < T_ * K_) {
#pragma unroll
                for (int ni = 0; ni < 2; ++ni) {
                    int gcol = bn + wc * 32 + ni * 16 + l15;
                    if (gcol < V_) Cexp[(size_t)grow * V_ + gcol] = ex[ni];
                }
            }
            rs += __shfl_xor(rs, 1);
            rs += __shfl_xor(rs, 2);
            rs += __shfl_xor(rs, 4);
            rs += __shfl_xor(rs, 8);
            if (l15 == 0 && grow < T_ * K_) atomicAdd(&bsum[grow], rs);
        }
    }
}

// ---------------------------------------------------------------------------
// beta[row][:] *= 1/bsum[row]  (softmax normalization), grid-stride.
// ---------------------------------------------------------------------------
__global__ __launch_bounds__(256) void beta_scale(
    float* __restrict__ beta, const float* __restrict__ bsum)
{
    const int total4 = T_ * K_ * (V_ / 4);
    for (int i = blockIdx.x * 256 + threadIdx.x; i < total4; i += gridDim.x * 256) {
        int row = i / (V_ / 4);
        float inv = 1.f / bsum[row];
        float4 v = ((const float4*)beta)[i];
        v.x *= inv; v.y *= inv; v.z *= inv; v.w *= inv;
        ((float4*)beta)[i] = v;
    }
}

// ---------------------------------------------------------------------------
// px / lnpx / nll accumulation. Grid (v-chunks, t). beta[t] staged in LDS.
// ---------------------------------------------------------------------------
__global__ __launch_bounds__(256) void px_kernel(
    const float* __restrict__ beta, const float* __restrict__ theta,
    const int* __restrict__ ts, const float* __restrict__ X,
    float* __restrict__ lnpx, float* __restrict__ nll_acc)
{
    __shared__ float sb[K_][256];
    int t = blockIdx.y;
    int tid = threadIdx.x;
    int v = blockIdx.x * 256 + tid;
    bool vok = v < V_;
    bool any = false;
    for (int b = 0; b < B_; ++b) any |= (ts[b] == t);
    if (!any) return;
    for (int k = 0; k < K_; ++k)
        sb[k][tid] = vok ? beta[((size_t)t * K_ + k) * V_ + v] : 0.f;
    __syncthreads();
    float acc = 0.f;
    for (int b = 0; b < B_; ++b) {
        if (ts[b] != t) continue;
        const float* th = theta + b * K_;
        float px = 0.f;
#pragma unroll
        for (int k = 0; k < K_; ++k) px += th[k] * sb[k][tid];
        float l = logf(px + 1e-6f);
        if (vok) {
            lnpx[(size_t)b * V_ + v] = l;
            acc += l * X[(size_t)b * V_ + v];
        }
    }
    for (int off = 32; off; off >>= 1) acc += __shfl_down(acc, off);
    __shared__ float red[4];
    int wid = tid >> 6, lane = tid & 63;
    if (lane == 0) red[wid] = acc;
    __syncthreads();
    if (tid == 0) atomicAdd(nll_acc, red[0] + red[1] + red[2] + red[3]);
}

// ---------------------------------------------------------------------------
// kl_alpha reduction over (K,T,E) in mu_q_alpha's native layout.
// ---------------------------------------------------------------------------
__global__ __launch_bounds__(256) void kl_alpha_kernel(
    const float* __restrict__ mu, const float* __restrict__ lsig,
    float* __restrict__ out)
{
    int idx = blockIdx.x * 256 + threadIdx.x;
    float term = 0.f;
    if (idx < K_ * T_ * E_) {
        int r = idx % (T_ * E_);
        int t = r / E_;
        float a = mu[idx];
        float q = lsig[idx];
        float pmu = (t > 0) ? mu[idx - E_] : 0.f;
        float pls = (t > 0) ? LOGD_ : 0.f;
        float d = a - pmu;
        term = 0.5f * ((expf(q) + d * d) / (expf(pls) + 1e-6f) - 1.f + pls - q);
    }
    for (int off = 32; off; off >>= 1) term += __shfl_down(term, off);
    __shared__ float red[4];
    int wid = threadIdx.x >> 6, lane = threadIdx.x & 63;
    if (lane == 0) red[wid] = term;
    __syncthreads();
    if (threadIdx.x == 0) atomicAdd(out, red[0] + red[1] + red[2] + red[3]);
}

__global__ void finalize_nll(const float* __restrict__ acc, float* __restrict__ out)
{
    *out = -acc[0] * (1.f / (float)B_);
}

// ---------------------------------------------------------------------------
extern "C" void kernel_launch(void* const* d_in, const int* in_sizes, int n_in,
                              void* d_out, int out_size, void* d_ws, size_t ws_size,
                              hipStream_t stream)
{
    const float* X          = (const float*)d_in[0];
    const int*   ts         = (const int*)d_in[1];
    const float* X_mean     = (const float*)d_in[2];
    const float* W_eta_map  = (const float*)d_in[3];
    const float* b_eta_map  = (const float*)d_in[4];
    const float* lstm_Wih   = (const float*)d_in[5];
    const float* lstm_Whh   = (const float*)d_in[6];
    const float* lstm_bih   = (const float*)d_in[7];
    const float* lstm_bhh   = (const float*)d_in[8];
    const float* W_qeta_mu  = (const float*)d_in[9];
    const float* b_qeta_mu  = (const float*)d_in[10];
    const float* W_qeta_ls  = (const float*)d_in[11];
    const float* b_qeta_ls  = (const float*)d_in[12];
    const float* W1         = (const float*)d_in[13];
    const float* b1         = (const float*)d_in[14];
    const float* W2         = (const float*)d_in[15];
    const float* b2         = (const float*)d_in[16];
    const float* W_qt_mu    = (const float*)d_in[17];
    const float* b_qt_mu    = (const float*)d_in[18];
    const float* W_qt_ls    = (const float*)d_in[19];
    const float* b_qt_ls    = (const float*)d_in[20];
    const float* mu_q_alpha = (const float*)d_in[21];
    const float* ls_q_alpha = (const float*)d_in[22];
    const float* emb        = (const float*)d_in[23];

    float* out     = (float*)d_out;
    float* o_theta = out;                          // [B,K]
    float* o_lnpx  = out + (size_t)B_ * K_;        // [B,V]
    float* o_beta  = o_lnpx + (size_t)B_ * V_;     // [T,K,V]
    float* o_scal  = o_beta + (size_t)T_ * K_ * V_; // nll, kl_alpha, kl_eta, kl_theta

    float* ws = (float*)d_ws;
    float* w_inv   = ws;               // 128
    float* w_rnn   = ws + 128;         // 12800
    float* w_seq0  = ws + 12928;       // 12800  (final LSTM layer out)
    float* w_houtA = ws + 38528;       // 12800  (layer-0 out)
    float* w_houtB = ws + 51328;       // 12800  (layer-1 out)
    float* w_cnt   = ws + 64640;       // 96 ints (3 counters, 128B apart)
    float* w_etas  = ws + 89728;       // 2500
    float* w_h1    = ws + 92228;       // 102400
    float* w_h2    = ws + 194628;      // 102400
    float* w_mu    = ws + 297028;      // 6400
    float* w_ls    = ws + 303428;      // 6400
    float* w_nll   = ws + 309828;      // 1
    float* w_bsum  = ws + 309832;      // 2500 (+pad to 312344)
    short* w_Ah    = (short*)(ws + 312344);   // 819200 shorts
    short* w_Al    = (short*)(ws + 721944);   // 819200 shorts

    // zero accumulators (d_out / d_ws are poisoned before every launch)
    hipMemsetAsync(o_scal, 0, 4 * sizeof(float), stream);
    hipMemsetAsync(w_h1, 0, (size_t)(102400 + 102400 + 6400 + 6400 + 1) * sizeof(float), stream);
    hipMemsetAsync(w_rnn, 0, (size_t)T_ * HE_ * sizeof(float), stream);
    hipMemsetAsync(w_cnt, 0, 96 * sizeof(int), stream);
    hipMemsetAsync(w_bsum, 0, (size_t)T_ * K_ * sizeof(float), stream);

    rowsum_inv<<<B_, 256, 0, stream>>>(X, w_inv);

    // rnn_in = X_mean @ W_eta_map^T + b_eta_map   [T,HE]
    // split-bf16 MFMA, split-K: 47 chunks x 640 (KP=30080), grid 2x1x47
    gemm_bf3<<<dim3(2, 1, 47), 512, 0, stream>>>(
        X_mean, V_, T_, W_eta_map, V_, HE_, V_, w_rnn, HE_, 640);
    bias_act<<<(T_ * HE_ + 255) / 256, 256, 0, stream>>>(
        w_rnn, b_eta_map, T_ * HE_, HE_, 2);

    // wavefront-pipelined 3-layer LSTM (3 x GLB blocks, flag-chained)
    lstm_pipe<<<3 * GLB, 256, 0, stream>>>(
        w_rnn, lstm_Wih, lstm_Whh, lstm_bih, lstm_bhh,
        w_houtA, w_houtB, w_seq0, (int*)w_cnt);

    // eta recurrence + kl_eta
    eta_scan<<<1, 256, 0, stream>>>(w_seq0, W_qeta_mu, b_qeta_mu,
                                    W_qeta_ls, b_qeta_ls, w_etas, o_scal + 2);

    // C1 = X @ W1[:, :V]^T via split-bf16 MFMA, split-K: 10 chunks x 3008,
    // grid 7x1x10; epilogue folds rowsum/eta/bias/tanh
    gemm_bf3<<<dim3((TH_ + 127) / 128, 1, 10), 512, 0, stream>>>(
        X, V_, B_, W1, V_ + K_, TH_, V_, w_h1, TH_, 3008);
    h1_epilogue<<<(B_ * TH_ + 255) / 256, 256, 0, stream>>>(
        w_h1, w_inv, w_etas, ts, W1, b1, w_h1);

    // h2 = tanh(h1 @ W2^T + b2), split-K 10x80 (f32, small)
    gemm_nt<<<dim3((TH_ + TN - 1) / TN, (B_ + TM - 1) / TM, 10), 256, 0, stream>>>(
        w_h1, TH_, B_, W2, TH_, TH_, TH_, w_h2, TH_, nullptr, 3, 80);
    bias_act<<<(B_ * TH_ + 255) / 256, 256, 0, stream>>>(
        w_h2, b2, B_ * TH_, TH_, 1);

    // mu_t / ls_t: K=800, split-K 25x32
    gemm_nt<<<dim3(1, (B_ + TM - 1) / TM, 25), 256, 0, stream>>>(
        w_h2, TH_, B_, W_qt_mu, TH_, K_, TH_, w_mu, K_, nullptr, 3, 32);
    gemm_nt<<<dim3(1, (B_ + TM - 1) / TM, 25), 256, 0, stream>>>(
        w_h2, TH_, B_, W_qt_ls, TH_, K_, TH_, w_ls, K_, nullptr, 3, 32);
    bias_act<<<(B_ * K_ + 255) / 256, 256, 0, stream>>>(
        w_mu, b_qt_mu, B_ * K_, K_, 2);
    bias_act<<<(B_ * K_ + 255) / 256, 256, 0, stream>>>(
        w_ls, b_qt_ls, B_ * K_, K_, 2);

    theta_kernel<<<B_, 64, 0, stream>>>(w_mu, w_ls, w_etas, ts, o_theta, o_scal + 3);

    // beta: alpha transpose+split, split-bf16 MFMA GEMM with fused exp/rowsum,
    // then normalize in place
    conv_alpha<<<(MPAD_ * KP_ + 255) / 256, 256, 0, stream>>>(mu_q_alpha, w_Ah, w_Al);
    gemm_beta<<<(NPAD_ / 128) * (MPAD_ / 128), 512, 0, stream>>>(
        w_Ah, w_Al, emb, o_beta, w_bsum);
    beta_scale<<<2048, 256, 0, stream>>>(o_beta, w_bsum);

    // px / lnpx / nll
    px_kernel<<<dim3((V_ + 255) / 256, T_), 256, 0, stream>>>(
        o_beta, o_theta, ts, X, o_lnpx, w_nll);

    kl_alpha_kernel<<<(K_ * T_ * E_ + 255) / 256, 256, 0, stream>>>(
        mu_q_alpha, ls_q_alpha, o_scal + 1);

    finalize_nll<<<1, 1, 0, stream>>>(w_nll, o_scal);
}